// Round 10
// baseline (82053.864 us; speedup 1.0000x reference)
//
#include <hip/hip_runtime.h>

#define B_ 1024
#define T_ 256
#define V_ 90
#define H_ 256
#define NTHR 512
#define NBLK 256
#define S_ ((size_t)B_*H_)

typedef unsigned short u16;
typedef __attribute__((ext_vector_type(8))) _Float16 f16x8;
typedef __attribute__((ext_vector_type(4))) float f32x4;

// ---------------- ws layout (float offsets) ----------------
constexpr size_t OFF_GH1C  = 0;
constexpr size_t OFF_GC1C  = OFF_GH1C + S_;
constexpr size_t OFF_GH1P  = OFF_GC1C + S_;
constexpr size_t OFF_GC1P  = OFF_GH1P + S_;
constexpr size_t OFF_LH1   = OFF_GC1P + S_;      // 2 buffers
constexpr size_t OFF_LC1   = OFF_LH1 + 2*S_;
constexpr size_t OFF_GH2C  = OFF_LC1 + 2*S_;
constexpr size_t OFF_GC2C  = OFF_GH2C + S_;
constexpr size_t OFF_GH2P  = OFF_GC2C + S_;
constexpr size_t OFF_GC2P  = OFF_GH2P + S_;
constexpr size_t OFF_LH2   = OFF_GC2P + S_;      // 2 buffers
constexpr size_t OFF_LC2   = OFF_LH2 + 2*S_;
constexpr size_t OFF_M1A   = OFF_LC2 + 2*S_;     // p1 partials (K-split)
constexpr size_t OFF_M1B   = OFF_M1A + (size_t)B_*512;
constexpr size_t OFF_M2A   = OFF_M1B + (size_t)B_*512;  // p2 partials
constexpr size_t OFF_M2B   = OFF_M2A + (size_t)B_*512;
constexpr size_t OFF_EX    = OFF_M2B + (size_t)B_*512;  // 2*1024*8
// fp16 packed weights (u16 counts halved into float units)
constexpr size_t OFF_WG1PK = OFF_EX + 2*B_*8;            // 256x2048 fp16
constexpr size_t OFF_WE1   = OFF_WG1PK + 256*2048/2;     // fp32 [8][2048pk]
constexpr size_t OFF_BG1   = OFF_WE1 + 8*2048;
constexpr size_t OFF_WL2PK = OFF_BG1 + 2048;             // 512x1024 fp16
constexpr size_t OFF_BL2   = OFF_WL2PK + 512*1024/2;
constexpr size_t OFF_WG2PK = OFF_BL2 + 1024;
constexpr size_t OFF_BG2   = OFF_WG2PK + 512*1024/2;
constexpr size_t OFF_WP1PK = OFF_BG2 + 1024;             // 1024x512 fp16
constexpr size_t OFF_WEP1  = OFF_WP1PK + 1024*512/2;
constexpr size_t OFF_WP2PK = OFF_WEP1 + 8*512;
constexpr size_t OFF_WEP2  = OFF_WP2PK + 1024*512/2;
constexpr size_t OFF_WB1   = OFF_WEP2 + 8*512;           // fp32 [512][256]
constexpr size_t OFF_WB2   = OFF_WB1 + 512*256;
constexpr size_t OFF_WOUT  = OFF_WB2 + 512*256;          // fp32 [256][96]
constexpr size_t OFF_BOUT  = OFF_WOUT + 256*96;
constexpr size_t OFF_BAR   = OFF_BOUT + 128;             // 8 XCD * 1024 uints
constexpr size_t WS_FLOATS = OFF_BAR + 8192;

struct InP {
  const int*   seq;
  const float* emb;
  const float *g1_Wih,*g1_Whh,*g1_bih,*g1_bhh;
  const float *g2_Wih,*g2_Whh,*g2_bih,*g2_bhh;
  const float *l1_Wih,*l1_Whh,*l1_bih,*l1_bhh;
  const float *l2_Wih,*l2_Whh,*l2_bih,*l2_bhh;
  const float *p1_W1,*p1_b1,*p1_W2,*p1_b2,*p1_W3,*p1_b3;
  const float *p2_W1,*p2_b1,*p2_W2,*p2_b2,*p2_W3,*p2_b3;
  const float *gfc_W,*gfc_b,*lfc_W,*lfc_b;
};

__device__ __forceinline__ float sig_(float x)  { return 1.f/(1.f+__expf(-x)); }
__device__ __forceinline__ float tanh_(float x) { return 1.f - 2.f/(__expf(2.f*x)+1.f); }
__device__ __forceinline__ u16 f2h(float v) {
  _Float16 h = (_Float16)v; return __builtin_bit_cast(unsigned short, h);
}

// ---- AGENT-scope (sc1) flag ops (R7-proven) ----
__device__ __forceinline__ unsigned ld_flag(const unsigned* p) {
  unsigned v;
  asm volatile("global_load_dword %0, %1, off sc1\n\ts_waitcnt vmcnt(0)"
               : "=v"(v) : "v"(p) : "memory");
  return v;
}
__device__ __forceinline__ void st_flag(unsigned* p, unsigned v) {
  asm volatile("global_store_dword %0, %1, off sc1\n\ts_waitcnt vmcnt(0)"
               :: "v"(p), "v"(v) : "memory");
}

// -------- per-XCD barrier: all-poll epoch flags (R9-proven) --------
__device__ __forceinline__ void gbar_x(unsigned* arr, int slot, unsigned ep)
{
  __syncthreads();                       // drains vmcnt(0): stores in L2
  if (threadIdx.x == 0) st_flag(&arr[slot*16], ep);
  if (threadIdx.x < 32) {
    int cap = 0;
    for (;;) {
      unsigned v = ld_flag(&arr[threadIdx.x*16]);
      if (v >= ep) break;
      __builtin_amdgcn_s_sleep(1);
      if (++cap > 200000) break;
    }
  }
  __syncthreads();
  asm volatile("buffer_inv sc0" ::: "memory");   // vL1 invalidate only
}

// ====== fp16 MFMA tile GEMM, ALL-REGISTER: 64 rows x 128 cols, 8 waves ======
// No LDS, no __syncthreads. Each lane loads its exact fragments from global:
//   A: 8 consecutive fp32 state elems [row = r0+wr*16+(l&15)][k=(l>>4)*8 ..+8)
//   B: fragment-major packed fp16: 16B at (chunk*tiles + wc*4+t)*512 + lane*8
// Depth-4 register pipeline (fully unrolled, static indices) => 384B/lane
// in flight; 8 waves drift freely => deep CU-level MLP.
// C/D: col=l&15, row=(l>>4)*4+reg   [HW-verified R8/R9]
template<int NCH, int NSEG, bool HASE, class FE>
__device__ __forceinline__ void mm_reg(
    const float* s0, const float* s1_,
    const u16* __restrict__ Wpk, int tiles,
    const float* WeP, int ldwe, const float* ex,
    int r0, int ct0, FE fe)
{
  const int tid  = threadIdx.x;
  const int lane = tid & 63;
  const int wr = (tid >> 6) & 3, wc = tid >> 8;
  const int row = r0 + wr*16 + (lane & 15);
  const int kq  = (lane >> 4) << 3;

  f32x4 acc[4] = {{0,0,0,0},{0,0,0,0},{0,0,0,0},{0,0,0,0}};

  constexpr int D = (NCH < 4) ? NCH : 4;
  float4 alo[D], ahi[D];
  f16x8  bfr[D][4];

  auto ldA = [&](int c, float4& lo, float4& hi) {
    const int k0 = c * 32;
    const float* S = (NSEG == 1) ? s0 : ((k0 < 256) ? s0 : s1_);
    const float* p = &S[(size_t)row*H_ + (k0 & 255) + kq];
    lo = *(const float4*)p; hi = *(const float4*)(p + 4);
  };
  auto ldB = [&](int c, f16x8* b) {
    const u16* base = Wpk + ((size_t)c*tiles + wc*4)*512 + lane*8;
#pragma unroll
    for (int t = 0; t < 4; ++t) b[t] = *(const f16x8*)(base + (size_t)t*512);
  };
  auto comp = [&](const float4& lo, const float4& hi, const f16x8* b) {
    float av[8] = {lo.x,lo.y,lo.z,lo.w,hi.x,hi.y,hi.z,hi.w};
    f16x8 a;
#pragma unroll
    for (int j = 0; j < 8; ++j) a[j] = (_Float16)av[j];
#pragma unroll
    for (int t = 0; t < 4; ++t)
      acc[t] = __builtin_amdgcn_mfma_f32_16x16x32_f16(a, b[t], acc[t], 0, 0, 0);
  };

#pragma unroll
  for (int c = 0; c < D; ++c) { ldA(c, alo[c], ahi[c]); ldB(c, bfr[c]); }
#pragma unroll
  for (int c = 0; c < NCH; ++c) {
    comp(alo[c % D], ahi[c % D], bfr[c % D]);
    if (c + D < NCH) { ldA(c + D, alo[c % D], ahi[c % D]); ldB(c + D, bfr[c % D]); }
  }

  if (HASE) {   // E-correction (K=8 embedding part), direct L1/L2 reads
#pragma unroll
    for (int t = 0; t < 4; ++t) {
      const int colL = ct0 + wc*64 + t*16 + (lane & 15);
      float w[8];
#pragma unroll
      for (int j = 0; j < 8; ++j) w[j] = WeP[j*ldwe + colL];
#pragma unroll
      for (int m = 0; m < 4; ++m) {
        const int rr = r0 + wr*16 + ((lane >> 4) << 2) + m;
        float s = 0.f;
#pragma unroll
        for (int j = 0; j < 8; ++j) s = __builtin_fmaf(ex[rr*8 + j], w[j], s);
        acc[t][m] += s;
      }
    }
  }
  fe(wr, wc, lane, acc);
}

// ---------------- MFMA epilogues (R8/R9-verified) ----------------
struct GateEpiM {
  const float* cin; float* ho; float* co; const float* bias_pk;
  int r0; int ct0; int hb0;
  __device__ void operator()(int wr, int wc, int lane, f32x4 (&acc)[4]) const {
    const int h = hb0 + wc*16 + (lane & 15);
    const int rbase = r0 + wr*16 + ((lane >> 4) << 2);
    float b[4];
#pragma unroll
    for (int t = 0; t < 4; ++t) b[t] = bias_pk[ct0 + wc*64 + t*16 + (lane & 15)];
#pragma unroll
    for (int m = 0; m < 4; ++m) {
      const size_t ix = (size_t)(rbase + m)*H_ + h;
      float gi = sig_(acc[0][m] + b[0]);
      float gf = sig_(acc[1][m] + b[1]);
      float gg = tanh_(acc[2][m] + b[2]);
      float go = sig_(acc[3][m] + b[3]);
      float cn = gf*cin[ix] + gi*gg;
      ho[ix] = go*tanh_(cn); co[ix] = cn;
    }
  }
};

struct MlpEpiM {
  float* dst; int r0; int ct0;
  __device__ void operator()(int wr, int wc, int lane, f32x4 (&acc)[4]) const {
    const int rbase = r0 + wr*16 + ((lane >> 4) << 2);
    const int c0 = ct0 + wc*64 + (lane & 15);
#pragma unroll
    for (int t = 0; t < 4; ++t)
#pragma unroll
      for (int m = 0; m < 4; ++m)
        dst[(size_t)(rbase + m)*512 + c0 + t*16] = acc[t][m];
  }
};

// ---- fused p-MLP2 + head + softmax + mix (K-split partials) ----
__device__ __forceinline__ void stage_F2(
    int rowbase,
    const float* mlpA, const float* mlpB, const float* b1,
    const float* WB, const float* b2,
    const float* W3, const float* b3,
    const float* lh, const float* lc,
    const float* ghp, const float* gcp,
    float* ghc, float* gcc)
{
  const int w = threadIdx.x >> 6, lane = threadIdx.x & 63;
  const int r0 = rowbase + w*2;
  const float* aA0 = mlpA + (size_t)r0*512; const float* aB0 = mlpB + (size_t)r0*512;
  const float* aA1 = aA0 + 512;             const float* aB1 = aB0 + 512;
  float m0[4] = {0.f,0.f,0.f,0.f}, m1[4] = {0.f,0.f,0.f,0.f};
  for (int k0 = 0; k0 < 512; k0 += 4) {
    float4 xa = *(const float4*)&aA0[k0];
    float4 xb = *(const float4*)&aB0[k0];
    float4 ya = *(const float4*)&aA1[k0];
    float4 yb = *(const float4*)&aB1[k0];
    float4 bb = *(const float4*)&b1[k0];
    float xv0[4] = { fmaxf(xa.x+xb.x+bb.x,0.f), fmaxf(xa.y+xb.y+bb.y,0.f),
                     fmaxf(xa.z+xb.z+bb.z,0.f), fmaxf(xa.w+xb.w+bb.w,0.f) };
    float xv1[4] = { fmaxf(ya.x+yb.x+bb.x,0.f), fmaxf(ya.y+yb.y+bb.y,0.f),
                     fmaxf(ya.z+yb.z+bb.z,0.f), fmaxf(ya.w+yb.w+bb.w,0.f) };
#pragma unroll
    for (int j = 0; j < 4; ++j) {
      float4 wv = *(const float4*)&WB[(size_t)(k0+j)*256 + lane*4];
      m0[0] = __builtin_fmaf(xv0[j], wv.x, m0[0]);
      m0[1] = __builtin_fmaf(xv0[j], wv.y, m0[1]);
      m0[2] = __builtin_fmaf(xv0[j], wv.z, m0[2]);
      m0[3] = __builtin_fmaf(xv0[j], wv.w, m0[3]);
      m1[0] = __builtin_fmaf(xv1[j], wv.x, m1[0]);
      m1[1] = __builtin_fmaf(xv1[j], wv.y, m1[1]);
      m1[2] = __builtin_fmaf(xv1[j], wv.z, m1[2]);
      m1[3] = __builtin_fmaf(xv1[j], wv.w, m1[3]);
    }
  }
  float4 b = *(const float4*)&b2[lane*4];
  float bb2[4] = {b.x,b.y,b.z,b.w};
#pragma unroll
  for (int j = 0; j < 4; ++j) {
    m0[j] = fmaxf(m0[j]+bb2[j], 0.f);
    m1[j] = fmaxf(m1[j]+bb2[j], 0.f);
  }
  float4 w30 = *(const float4*)&W3[lane*4];
  float4 w31 = *(const float4*)&W3[256 + lane*4];
  float w0v[4] = {w30.x,w30.y,w30.z,w30.w};
  float w1v[4] = {w31.x,w31.y,w31.z,w31.w};
  float d00=0.f, d01=0.f, d10=0.f, d11=0.f;
#pragma unroll
  for (int j = 0; j < 4; ++j) {
    d00 = __builtin_fmaf(m0[j], w0v[j], d00);
    d01 = __builtin_fmaf(m0[j], w1v[j], d01);
    d10 = __builtin_fmaf(m1[j], w0v[j], d10);
    d11 = __builtin_fmaf(m1[j], w1v[j], d11);
  }
#pragma unroll
  for (int off = 32; off; off >>= 1) {
    d00 += __shfl_xor(d00, off, 64); d01 += __shfl_xor(d01, off, 64);
    d10 += __shfl_xor(d10, off, 64); d11 += __shfl_xor(d11, off, 64);
  }
  d00 += b3[0]; d01 += b3[1]; d10 += b3[0]; d11 += b3[1];
  float mxa = fmaxf(d00, d01), mxb = fmaxf(d10, d11);
  float e00 = __expf(d00-mxa), e01 = __expf(d01-mxa);
  float e10 = __expf(d10-mxb), e11 = __expf(d11-mxb);
  float ia = 1.f/(e00+e01), ib = 1.f/(e10+e11);
  float p0a = e00*ia, p1a = e01*ia;
  float p0b = e10*ib, p1b = e11*ib;
#pragma unroll
  for (int rr = 0; rr < 2; ++rr) {
    const float p0 = rr ? p0b : p0a, p1 = rr ? p1b : p1a;
    const size_t ix = (size_t)(r0+rr)*H_ + lane*4;
    float4 lv = *(const float4*)&lh[ix];
    float4 gv = *(const float4*)&ghp[ix];
    float4 o;
    o.x = p0*lv.x + p1*gv.x; o.y = p0*lv.y + p1*gv.y;
    o.z = p0*lv.z + p1*gv.z; o.w = p0*lv.w + p1*gv.w;
    *(float4*)&ghc[ix] = o;
    lv = *(const float4*)&lc[ix];
    gv = *(const float4*)&gcp[ix];
    o.x = p0*lv.x + p1*gv.x; o.y = p0*lv.y + p1*gv.y;
    o.z = p0*lv.z + p1*gv.z; o.w = p0*lv.w + p1*gv.w;
    *(float4*)&gcc[ix] = o;
  }
}

// -------- output projection, 16 rows per block (2 rows/wave) --------
__device__ __forceinline__ void stage_OUT2(
    const float* gh2c, const float* WOUT, const float* BOUT,
    float* out, int rbase, int tt)
{
  const int w = threadIdx.x >> 6, lane = threadIdx.x & 63;
  const bool two = lane < (V_ - 64);
#pragma unroll
  for (int rr = 0; rr < 2; ++rr) {
    const int r = rbase + w*2 + rr;
    const float* arow = gh2c + (size_t)r * H_;
    float acc0 = 0.f, acc1 = 0.f;
    for (int k0 = 0; k0 < 256; k0 += 4) {
      float4 a4 = *(const float4*)&arow[k0];
      float av[4] = {a4.x, a4.y, a4.z, a4.w};
#pragma unroll
      for (int j = 0; j < 4; ++j) {
        const float* wr_ = &WOUT[(size_t)(k0+j)*96];
        acc0 = __builtin_fmaf(av[j], wr_[lane], acc0);
        if (two) acc1 = __builtin_fmaf(av[j], wr_[64+lane], acc1);
      }
    }
    out[((size_t)r*V_ + lane)*T_ + tt] = acc0 + BOUT[lane];
    if (two) out[((size_t)r*V_ + 64 + lane)*T_ + tt] = acc1 + BOUT[64+lane];
  }
}

// ---------------- setup: zero states/bar, gather ex0, pack fp16 weights ----
__global__ void k_setup(InP in, float* __restrict__ ws)
{
  const size_t nthr = (size_t)gridDim.x * blockDim.x;
  const size_t t0 = (size_t)blockIdx.x * blockDim.x + threadIdx.x;

  for (size_t i = t0; i < 16*S_; i += nthr) ws[i] = 0.f;
  for (size_t i = t0; i < 8192; i += nthr) ((unsigned*)(ws + OFF_BAR))[i] = 0u;

  for (size_t i = t0; i < (size_t)B_*8; i += nthr) {
    int r = (int)(i >> 3), j = (int)(i & 7);
    ws[OFF_EX + i] = in.emb[(size_t)in.seq[(size_t)r*T_]*8 + j];
  }

  // WG1pk: K=256, N=2048 (Whh of g1|l1, gate-grouped cols), fragment-major fp16
  {
    u16* dst = (u16*)(ws + OFF_WG1PK);
    for (size_t i = t0; i < (size_t)8*128*512; i += nthr) {
      int e = (int)(i & 7), lane = (int)((i >> 3) & 63);
      int tile = (int)((i >> 9) & 127), ck = (int)(i >> 16);
      int p = tile*16 + (lane & 15);
      int k = ck*32 + ((lane >> 4) << 3) + e;
      int cell = p >> 10, q = p & 1023;
      int h = ((q >> 6) << 4) + (q & 15), g = (q >> 4) & 3, R = g*256 + h;
      float w = (cell ? in.l1_Whh : in.g1_Whh)[(size_t)R*256 + k];
      dst[((size_t)(ck*128 + tile))*512 + lane*8 + e] = f2h(w);
    }
  }
  for (size_t i = t0; i < (size_t)8*2048; i += nthr) {
    int j = (int)(i >> 11), p = (int)(i & 2047);
    int cell = p >> 10, q = p & 1023;
    int h = ((q >> 6) << 4) + (q & 15), g = (q >> 4) & 3, R = g*256 + h;
    ws[OFF_WE1 + (size_t)j*2048 + p] = (cell ? in.l1_Wih : in.g1_Wih)[(size_t)R*8 + j];
  }
  for (size_t i = t0; i < 2048; i += nthr) {
    int p = (int)i, cell = p >> 10, q = p & 1023;
    int h = ((q >> 6) << 4) + (q & 15), g = (q >> 4) & 3, R = g*256 + h;
    ws[OFF_BG1 + i] = cell ? (in.l1_bih[R] + in.l1_bhh[R]) : (in.g1_bih[R] + in.g1_bhh[R]);
  }

  // WL2pk / WG2pk: K=512, N=1024
  for (int which = 0; which < 2; ++which) {
    u16* dst = (u16*)(ws + (which ? OFF_WG2PK : OFF_WL2PK));
    const float* Wih = which ? in.g2_Wih : in.l2_Wih;
    const float* Whh = which ? in.g2_Whh : in.l2_Whh;
    for (size_t i = t0; i < (size_t)16*64*512; i += nthr) {
      int e = (int)(i & 7), lane = (int)((i >> 3) & 63);
      int tile = (int)((i >> 9) & 63), ck = (int)(i >> 15);
      int p = tile*16 + (lane & 15);
      int k = ck*32 + ((lane >> 4) << 3) + e;
      int h = ((p >> 6) << 4) + (p & 15), g = (p >> 4) & 3, R = g*256 + h;
      float w = (k < 256) ? Wih[(size_t)R*256 + k] : Whh[(size_t)R*256 + (k-256)];
      dst[((size_t)(ck*64 + tile))*512 + lane*8 + e] = f2h(w);
    }
  }
  for (size_t i = t0; i < 2*1024; i += nthr) {
    int which = (int)(i >> 10), p = (int)(i & 1023);
    int h = ((p >> 6) << 4) + (p & 15), g = (p >> 4) & 3, R = g*256 + h;
    float v = which ? (in.g2_bih[R] + in.g2_bhh[R]) : (in.l2_bih[R] + in.l2_bhh[R]);
    ws[(which ? OFF_BG2 : OFF_BL2) + p] = v;
  }

  // WP1pk / WP2pk: K=1024, N=512 (natural cols)
  for (int which = 0; which < 2; ++which) {
    u16* dst = (u16*)(ws + (which ? OFF_WP2PK : OFF_WP1PK));
    const float* W = which ? in.p2_W1 : in.p1_W1;
    for (size_t i = t0; i < (size_t)32*32*512; i += nthr) {
      int e = (int)(i & 7), lane = (int)((i >> 3) & 63);
      int tile = (int)((i >> 9) & 31), ck = (int)(i >> 14);
      int p = tile*16 + (lane & 15);
      int k = ck*32 + ((lane >> 4) << 3) + e;
      dst[((size_t)(ck*32 + tile))*512 + lane*8 + e] = f2h(W[(size_t)p*1032 + 8 + k]);
    }
  }
  for (size_t i = t0; i < (size_t)2*8*512; i += nthr) {
    int which = (int)(i / (8*512));
    int idx = (int)(i - (size_t)which*8*512);
    int j = idx >> 9, p = idx & 511;
    const float* W = which ? in.p2_W1 : in.p1_W1;
    ws[(which ? OFF_WEP2 : OFF_WEP1) + (size_t)j*512 + p] = W[(size_t)p*1032 + j];
  }

  for (size_t i = t0; i < (size_t)2*512*256; i += nthr) {
    int which = (int)(i / (512*256));
    int idx = (int)(i - (size_t)which*512*256);
    int k = idx >> 8, n = idx & 255;
    const float* W = which ? in.p2_W2 : in.p1_W2;
    ws[(which ? OFF_WB2 : OFF_WB1) + idx] = W[(size_t)n*512 + k];
  }
  for (size_t i = t0; i < (size_t)256*96; i += nthr) {
    int k = (int)(i / 96), c = (int)(i - (size_t)k*96);
    float v = 0.f;
    if (c < V_) v = 0.5f*(in.gfc_W[(size_t)c*256 + k] + in.lfc_W[(size_t)c*256 + k]);
    ws[OFF_WOUT + i] = v;
  }
  for (size_t i = t0; i < 96; i += nthr)
    ws[OFF_BOUT + i] = (i < V_) ? 0.5f*(in.gfc_b[i] + in.lfc_b[i]) : 0.f;
}

// ------------- main persistent kernel: 3-phase pipeline, reg-GEMMs -------------
__global__ __launch_bounds__(NTHR) void k_main(InP in, float* ws, float* __restrict__ out)
{
  // occupancy pin (match R9's proven 1-block/CU footprint): 30KB static
  // (volatile-touched so it isn't DCE'd) + 52KB dynamic at launch.
  __shared__ __attribute__((aligned(16))) volatile float s_pin[7680];
  __shared__ unsigned s_slot;

  float* GH1C = ws + OFF_GH1C;  float* GC1C = ws + OFF_GC1C;
  float* GH1P = ws + OFF_GH1P;  float* GC1P = ws + OFF_GC1P;
  float* LH1  = ws + OFF_LH1;   float* LC1  = ws + OFF_LC1;
  float* GH2C = ws + OFF_GH2C;  float* GC2C = ws + OFF_GC2C;
  float* GH2P = ws + OFF_GH2P;  float* GC2P = ws + OFF_GC2P;
  float* LH2  = ws + OFF_LH2;   float* LC2  = ws + OFF_LC2;
  float* M1A  = ws + OFF_M1A;   float* M1B  = ws + OFF_M1B;
  float* M2A  = ws + OFF_M2A;   float* M2B  = ws + OFF_M2B;
  float* EXB  = ws + OFF_EX;
  const u16* WG1PK = (const u16*)(ws + OFF_WG1PK);
  const u16* WL2PK = (const u16*)(ws + OFF_WL2PK);
  const u16* WG2PK = (const u16*)(ws + OFF_WG2PK);
  const u16* WP1PK = (const u16*)(ws + OFF_WP1PK);
  const u16* WP2PK = (const u16*)(ws + OFF_WP2PK);
  const float* WE1  = ws + OFF_WE1;  const float* BG1P = ws + OFF_BG1;
  const float* BL2P = ws + OFF_BL2;  const float* BG2P = ws + OFF_BG2;
  const float* WEP1 = ws + OFF_WEP1; const float* WEP2 = ws + OFF_WEP2;
  const float* WB1  = ws + OFF_WB1;  const float* WB2  = ws + OFF_WB2;
  const float* WOUT = ws + OFF_WOUT; const float* BOUT = ws + OFF_BOUT;

  unsigned xcc;
  asm volatile("s_getreg_b32 %0, hwreg(HW_REG_XCC_ID)" : "=s"(xcc));
  xcc &= 7u;
  unsigned* barx = ((unsigned*)(ws + OFF_BAR)) + xcc*1024;
  unsigned* arr  = barx;
  unsigned* reg  = barx + 544;
  if (threadIdx.x == 0) {
    s_slot = __hip_atomic_fetch_add(reg, 1u, __ATOMIC_RELAXED, __HIP_MEMORY_SCOPE_AGENT);
    s_pin[0] = (float)s_slot;          // volatile touch: keeps 30KB static LDS
  }
  __syncthreads();
  const int slot  = (int)(s_slot & 31u);
  const int rows0 = (int)xcc * 128;
  unsigned ep = 0;

  // cycle n: P_A gates1(n) || g2(n-1); P_B MLP1(n) || MLP2(n-1);
  //          P_C l2(n) || mix1(n)+ex(n+1) || mix2(n-1)+out(n-1)
  for (int n = 0; n <= T_; ++n) {
    const int sel = n & 1;
    const float* ex  = EXB + sel*(B_*8);         // ex(n)
    const float* exm = EXB + (sel^1)*(B_*8);     // ex(n-1)
    float* lh1o = LH1 + sel*S_;   float* lh1n = LH1 + (sel^1)*S_;
    float* lc1o = LC1 + sel*S_;   float* lc1n = LC1 + (sel^1)*S_;
    float* lh2o = LH2 + sel*S_;   float* lh2n = LH2 + (sel^1)*S_;  // lh2o == lh2n(n-1)
    float* lc2o = LC2 + sel*S_;   float* lc2n = LC2 + (sel^1)*S_;

    // ===== P_A =====
    if (slot < 16) {
      if (n < T_) {
        const int rt = slot & 1, cq = slot >> 1;          // cq 0..7 (256-col quads)
        const int r0 = rows0 + rt*64;
        const int cell = cq >> 2;
        const float* hin = cell ? lh1o : GH1C;
#pragma unroll
        for (int half = 0; half < 2; ++half) {
          const int ct0 = cq*256 + half*128;
          GateEpiM epi{ cell ? lc1o : GC1C,
                        cell ? lh1n : GH1P,
                        cell ? lc1n : GC1P,
                        BG1P, r0, ct0, ((ct0 & 1023) >> 6) << 4 };
          mm_reg<8,1,true>(hin, nullptr,
                           WG1PK + (size_t)(ct0 >> 4)*512, 128,
                           WE1, 2048, ex, r0, ct0, epi);
        }
      }
    } else if (n >= 1) {
      const int s2 = slot - 16;
      const int rt = s2 & 1, ct = s2 >> 1;                // ct 0..7
      const int r0 = rows0 + rt*64, ct0 = ct*128;
      GateEpiM epi{ GC2C, GH2P, GC2P, BG2P, r0, ct0, (ct0 >> 6) << 4 };
      mm_reg<16,2,false>(GH1C, GH2C,
                         WG2PK + (size_t)(ct0 >> 4)*512, 64,
                         nullptr, 0, nullptr, r0, ct0, epi);
    }
    gbar_x(arr, slot, ++ep);

    // ===== P_B =====
    if (slot < 16) {
      if (n < T_) {
        const int rt = slot & 1, q = slot >> 1;
        const int ct = q & 3, kh = q >> 2;
        const int r0 = rows0 + rt*64, ct0 = ct*128;
        if (kh == 0) {
          MlpEpiM epi{ M1A, r0, ct0 };
          mm_reg<16,2,false>(GH1P, GC1P,
                             WP1PK + (size_t)(ct0 >> 4)*512, 32,
                             nullptr, 0, nullptr, r0, ct0, epi);
        } else {
          MlpEpiM epi{ M1B, r0, ct0 };
          mm_reg<16,2,true>(lh1n, lc1n,
                            WP1PK + (size_t)16*(32*512) + (size_t)(ct0 >> 4)*512, 32,
                            WEP1, 512, ex, r0, ct0, epi);
        }
      }
    } else if (n >= 1) {
      const int s2 = slot - 16;
      const int rt = s2 & 1, q = s2 >> 1;
      const int ct = q & 3, kh = q >> 2;
      const int r0 = rows0 + rt*64, ct0 = ct*128;
      if (kh == 0) {
        MlpEpiM epi{ M2A, r0, ct0 };
        mm_reg<16,2,false>(GH2P, GC2P,
                           WP2PK + (size_t)(ct0 >> 4)*512, 32,
                           nullptr, 0, nullptr, r0, ct0, epi);
      } else {
        MlpEpiM epi{ M2B, r0, ct0 };
        mm_reg<16,2,true>(lh2o, lc2o,                 // lh2n(n-1), lc2n(n-1)
                          WP2PK + (size_t)16*(32*512) + (size_t)(ct0 >> 4)*512, 32,
                          WEP2, 512, exm, r0, ct0, epi);
      }
    }
    gbar_x(arr, slot, ++ep);

    // ===== P_C =====
    if (slot < 16) {
      if (n < T_) {
        const int rt = slot & 1, ct = slot >> 1;          // ct 0..7
        const int r0 = rows0 + rt*64, ct0 = ct*128;
        GateEpiM epi{ lc2o, lh2n, lc2n, BL2P, r0, ct0, (ct0 >> 6) << 4 };
        mm_reg<16,2,false>(lh1n, lh2o,
                           WL2PK + (size_t)(ct0 >> 4)*512, 64,
                           nullptr, 0, nullptr, r0, ct0, epi);
      }
    } else if (slot < 24) {
      if (n < T_) {
        const int rb = rows0 + (slot-16)*16;
        stage_F2(rb, M1A, M1B, in.p1_b1, WB1, in.p1_b2, in.p1_W3, in.p1_b3,
                 lh1n, lc1n, GH1P, GC1P, GH1C, GC1C);
        if (n + 1 < T_ && threadIdx.x < 128) {
          const int r = rb + (threadIdx.x >> 3), j = threadIdx.x & 7;
          EXB[(sel^1)*(B_*8) + r*8 + j] =
              in.emb[(size_t)in.seq[(size_t)r*T_ + n + 1]*8 + j];
        }
      }
    } else {
      if (n >= 1) {
        const int rb = rows0 + (slot-24)*16;
        stage_F2(rb, M2A, M2B, in.p2_b1, WB2, in.p2_b2, in.p2_W3, in.p2_b3,
                 lh2o, lc2o, GH2P, GC2P, GH2C, GC2C);
        __syncthreads();
        stage_OUT2(GH2C, WOUT, BOUT, out, rb, n-1);
      }
    }
    gbar_x(arr, slot, ++ep);
  }
}

// ---------------- host ----------------
extern "C" void kernel_launch(void* const* d_in, const int* in_sizes, int n_in,
                              void* d_out, int out_size, void* d_ws, size_t ws_size,
                              hipStream_t stream)
{
  if (ws_size < WS_FLOATS * sizeof(float)) return;

  InP in;
  in.seq    = (const int*)  d_in[0];
  in.emb    = (const float*)d_in[1];
  in.g1_Wih = (const float*)d_in[2];  in.g1_Whh = (const float*)d_in[3];
  in.g1_bih = (const float*)d_in[4];  in.g1_bhh = (const float*)d_in[5];
  in.g2_Wih = (const float*)d_in[6];  in.g2_Whh = (const float*)d_in[7];
  in.g2_bih = (const float*)d_in[8];  in.g2_bhh = (const float*)d_in[9];
  in.l1_Wih = (const float*)d_in[10]; in.l1_Whh = (const float*)d_in[11];
  in.l1_bih = (const float*)d_in[12]; in.l1_bhh = (const float*)d_in[13];
  in.l2_Wih = (const float*)d_in[14]; in.l2_Whh = (const float*)d_in[15];
  in.l2_bih = (const float*)d_in[16]; in.l2_bhh = (const float*)d_in[17];
  in.p1_W1  = (const float*)d_in[18]; in.p1_b1  = (const float*)d_in[19];
  in.p1_W2  = (const float*)d_in[20]; in.p1_b2  = (const float*)d_in[21];
  in.p1_W3  = (const float*)d_in[22]; in.p1_b3  = (const float*)d_in[23];
  in.p2_W1  = (const float*)d_in[24]; in.p2_b1  = (const float*)d_in[25];
  in.p2_W2  = (const float*)d_in[26]; in.p2_b2  = (const float*)d_in[27];
  in.p2_W3  = (const float*)d_in[28]; in.p2_b3  = (const float*)d_in[29];
  in.gfc_W  = (const float*)d_in[30]; in.gfc_b  = (const float*)d_in[31];
  in.lfc_W  = (const float*)d_in[32]; in.lfc_b  = (const float*)d_in[33];

  float* ws  = (float*)d_ws;
  float* out = (float*)d_out;

  k_setup<<<512, 256, 0, stream>>>(in, ws);
  k_main <<<NBLK, NTHR, 53248, stream>>>(in, ws, out);   // dyn LDS: 1 block/CU pin
}

// Round 11
// 67757.953 us; speedup vs baseline: 1.2110x; 1.2110x over previous
//
#include <hip/hip_runtime.h>

#define B_ 1024
#define T_ 256
#define V_ 90
#define H_ 256
#define NTHR 512
#define NBLK 256
#define S_ ((size_t)B_*H_)

typedef unsigned short u16;
typedef __attribute__((ext_vector_type(8))) _Float16 f16x8;
typedef __attribute__((ext_vector_type(4))) _Float16 f16x4;
typedef __attribute__((ext_vector_type(4))) float f32x4;

// ---------------- ws layout (float offsets) ----------------
constexpr size_t OFF_GH1C  = 0;
constexpr size_t OFF_GC1C  = OFF_GH1C + S_;
constexpr size_t OFF_GH1P  = OFF_GC1C + S_;
constexpr size_t OFF_GC1P  = OFF_GH1P + S_;
constexpr size_t OFF_LH1   = OFF_GC1P + S_;      // 2 buffers
constexpr size_t OFF_LC1   = OFF_LH1 + 2*S_;
constexpr size_t OFF_GH2C  = OFF_LC1 + 2*S_;
constexpr size_t OFF_GC2C  = OFF_GH2C + S_;
constexpr size_t OFF_GH2P  = OFF_GC2C + S_;
constexpr size_t OFF_GC2P  = OFF_GH2P + S_;
constexpr size_t OFF_LH2   = OFF_GC2P + S_;      // 2 buffers
constexpr size_t OFF_LC2   = OFF_LH2 + 2*S_;
constexpr size_t OFF_M1A   = OFF_LC2 + 2*S_;     // p1 partials (K-split)
constexpr size_t OFF_M1B   = OFF_M1A + (size_t)B_*512;
constexpr size_t OFF_M2A   = OFF_M1B + (size_t)B_*512;  // p2 partials
constexpr size_t OFF_M2B   = OFF_M2A + (size_t)B_*512;
constexpr size_t OFF_EX    = OFF_M2B + (size_t)B_*512;  // 2*1024*8
// fp16 packed weights, per-block-contiguous 64KB slices
constexpr size_t OFF_WG1PK = OFF_EX + 2*B_*8;            // 16 blk x 32768 u16
constexpr size_t OFF_WE1   = OFF_WG1PK + 256*2048/2;     // fp32 [8][2048pk]
constexpr size_t OFF_BG1   = OFF_WE1 + 8*2048;
constexpr size_t OFF_WL2PK = OFF_BG1 + 2048;             // 16 blk x 32768 u16
constexpr size_t OFF_BL2   = OFF_WL2PK + 512*1024/2;
constexpr size_t OFF_WG2PK = OFF_BL2 + 1024;
constexpr size_t OFF_BG2   = OFF_WG2PK + 512*1024/2;
constexpr size_t OFF_WP1PK = OFF_BG2 + 1024;             // 16 blk x 32768 u16
constexpr size_t OFF_WEP1  = OFF_WP1PK + 1024*512/2;
constexpr size_t OFF_WP2PK = OFF_WEP1 + 8*512;
constexpr size_t OFF_WEP2  = OFF_WP2PK + 1024*512/2;
constexpr size_t OFF_WB1   = OFF_WEP2 + 8*512;           // fp16 [512][256]
constexpr size_t OFF_WB2   = OFF_WB1 + 512*256/2;
constexpr size_t OFF_WOUT  = OFF_WB2 + 512*256/2;        // fp32 [256][96]
constexpr size_t OFF_BOUT  = OFF_WOUT + 256*96;
constexpr size_t OFF_BAR   = OFF_BOUT + 128;             // 8 XCD * 1024 uints
constexpr size_t WS_FLOATS = OFF_BAR + 8192;

struct InP {
  const int*   seq;
  const float* emb;
  const float *g1_Wih,*g1_Whh,*g1_bih,*g1_bhh;
  const float *g2_Wih,*g2_Whh,*g2_bih,*g2_bhh;
  const float *l1_Wih,*l1_Whh,*l1_bih,*l1_bhh;
  const float *l2_Wih,*l2_Whh,*l2_bih,*l2_bhh;
  const float *p1_W1,*p1_b1,*p1_W2,*p1_b2,*p1_W3,*p1_b3;
  const float *p2_W1,*p2_b1,*p2_W2,*p2_b2,*p2_W3,*p2_b3;
  const float *gfc_W,*gfc_b,*lfc_W,*lfc_b;
};

__device__ __forceinline__ float sig_(float x)  { return 1.f/(1.f+__expf(-x)); }
__device__ __forceinline__ float tanh_(float x) { return 1.f - 2.f/(__expf(2.f*x)+1.f); }
__device__ __forceinline__ u16 f2h(float v) {
  _Float16 h = (_Float16)v; return __builtin_bit_cast(unsigned short, h);
}

// ---- AGENT-scope (sc1) flag ops (R7-proven) ----
__device__ __forceinline__ unsigned ld_flag(const unsigned* p) {
  unsigned v;
  asm volatile("global_load_dword %0, %1, off sc1\n\ts_waitcnt vmcnt(0)"
               : "=v"(v) : "v"(p) : "memory");
  return v;
}
__device__ __forceinline__ void st_flag(unsigned* p, unsigned v) {
  asm volatile("global_store_dword %0, %1, off sc1\n\ts_waitcnt vmcnt(0)"
               :: "v"(p), "v"(v) : "memory");
}

// -------- per-XCD barrier: all-poll epoch flags (R9-proven) --------
__device__ __forceinline__ void gbar_x(unsigned* arr, int slot, unsigned ep)
{
  __syncthreads();                       // drains vmcnt(0): stores in L2
  if (threadIdx.x == 0) st_flag(&arr[slot*16], ep);
  if (threadIdx.x < 32) {
    int cap = 0;
    for (;;) {
      unsigned v = ld_flag(&arr[threadIdx.x*16]);
      if (v >= ep) break;
      __builtin_amdgcn_s_sleep(1);
      if (++cap > 200000) break;
    }
  }
  __syncthreads();
  asm volatile("buffer_inv sc0" ::: "memory");   // vL1 invalidate only
}

// -------- async weight DMA: 64KB contiguous global -> dynamic LDS --------
__device__ __forceinline__ void gl_lds16(const void* g, void* l) {
  __builtin_amdgcn_global_load_lds(
      (const __attribute__((address_space(1))) unsigned int*)g,
      (__attribute__((address_space(3))) unsigned int*)l, 16, 0, 0);
}
__device__ __forceinline__ void dma64(const u16* src) {
  extern __shared__ u16 dynB[];
  const int wv = threadIdx.x >> 6, lane = threadIdx.x & 63;
  const char* g = (const char*)src + lane*16;
  char* l = (char*)dynB;
#pragma unroll
  for (int j = 0; j < 8; ++j) {
    const int ofs = (wv*8 + j) * 1024;     // 8 waves x 8KB = 64KB
    gl_lds16(g + ofs, l + ofs);
  }
}

// ====== fp16 MFMA tile GEMM: 128 rows x (TPW*16) cols, 8 row-wave-strips ======
// B pre-DMA'd into dynB as [chunk][tile 0..TPW-1][lane frag 512 u16].
// A: per-lane direct global (8 fp32), depth-4 register ring, NO syncs in loop.
// A frag: lane&15 = row, k = (lane>>4)*8 + e.  C/D: col=l&15, row=(l>>4)*4+reg.
template<int NCH, int NSEG, bool HASE, int TPW, class FE>
__device__ __forceinline__ void mm_lds(
    const float* s0, const float* s1_,
    const float* WeP, int ldwe, const float* ex,
    int rows0, int ct0, FE fe)
{
  extern __shared__ u16 dynB[];
  const int tid = threadIdx.x, lane = tid & 63, wr = tid >> 6;
  const int row = rows0 + wr*16 + (lane & 15);
  const int kq  = (lane >> 4) << 3;

  asm volatile("s_waitcnt vmcnt(0)" ::: "memory");   // DMA (this wave) done
  __syncthreads();                                    // all waves' DMA visible

  f32x4 acc[TPW];
#pragma unroll
  for (int t = 0; t < TPW; ++t) acc[t] = (f32x4){0,0,0,0};

  float4 alo[4], ahi[4];
  auto ldA = [&](int c, float4& lo, float4& hi) {
    const int k0 = c * 32;
    const float* S = (NSEG == 1) ? s0 : ((k0 < 256) ? s0 : s1_);
    const float* p = &S[(size_t)row*H_ + (k0 & 255) + kq];
    lo = *(const float4*)p; hi = *(const float4*)(p + 4);
  };
  auto comp = [&](int c, const float4& lo, const float4& hi) {
    float av[8] = {lo.x,lo.y,lo.z,lo.w,hi.x,hi.y,hi.z,hi.w};
    f16x8 a;
#pragma unroll
    for (int j = 0; j < 8; ++j) a[j] = (_Float16)av[j];
#pragma unroll
    for (int t = 0; t < TPW; ++t) {
      f16x8 b = *(const f16x8*)(dynB + (size_t)(c*TPW + t)*512 + lane*8);
      acc[t] = __builtin_amdgcn_mfma_f32_16x16x32_f16(a, b, acc[t], 0, 0, 0);
    }
  };

#pragma unroll
  for (int c = 0; c < 4; ++c) ldA(c, alo[c], ahi[c]);
#pragma unroll
  for (int c = 0; c < NCH; ++c) {
    comp(c, alo[c & 3], ahi[c & 3]);
    if (c + 4 < NCH) ldA(c + 4, alo[c & 3], ahi[c & 3]);
  }

  if (HASE) {   // E-correction (K=8 embedding part), direct L2 reads
#pragma unroll
    for (int t = 0; t < TPW; ++t) {
      const int colL = ct0 + t*16 + (lane & 15);
      float w[8];
#pragma unroll
      for (int j = 0; j < 8; ++j) w[j] = WeP[j*ldwe + colL];
#pragma unroll
      for (int m = 0; m < 4; ++m) {
        const int rr = rows0 + wr*16 + ((lane >> 4) << 2) + m;
        float s = 0.f;
#pragma unroll
        for (int j = 0; j < 8; ++j) s = __builtin_fmaf(ex[rr*8 + j], w[j], s);
        acc[t][m] += s;
      }
    }
  }
  fe(wr, lane, acc);
}

// ---------------- MFMA epilogues ----------------
template<int TPW>
struct GateEpiM {
  const float* cin; float* ho; float* co; const float* bias_pk;
  int rows0; int ct0;
  __device__ void operator()(int wr, int lane, f32x4 (&acc)[TPW]) const {
    const int rbase = rows0 + wr*16 + ((lane >> 4) << 2);
#pragma unroll
    for (int gi = 0; gi < TPW/4; ++gi) {
      const int cb = ct0 + gi*64;
      const int h = (((cb & 1023) >> 6) << 4) + (lane & 15);
      float b[4];
#pragma unroll
      for (int t = 0; t < 4; ++t) b[t] = bias_pk[cb + t*16 + (lane & 15)];
#pragma unroll
      for (int m = 0; m < 4; ++m) {
        const size_t ix = (size_t)(rbase + m)*H_ + h;
        float gI = sig_(acc[gi*4+0][m] + b[0]);
        float gF = sig_(acc[gi*4+1][m] + b[1]);
        float gG = tanh_(acc[gi*4+2][m] + b[2]);
        float gO = sig_(acc[gi*4+3][m] + b[3]);
        float cn = gF*cin[ix] + gI*gG;
        ho[ix] = gO*tanh_(cn); co[ix] = cn;
      }
    }
  }
};

struct MlpEpiM {
  float* dst; int rows0; int ct0;
  __device__ void operator()(int wr, int lane, f32x4 (&acc)[4]) const {
    const int rbase = rows0 + wr*16 + ((lane >> 4) << 2);
    const int c0 = ct0 + (lane & 15);
#pragma unroll
    for (int t = 0; t < 4; ++t)
#pragma unroll
      for (int m = 0; m < 4; ++m)
        dst[(size_t)(rbase + m)*512 + c0 + t*16] = acc[t][m];
  }
};

// ---- fused p-MLP2(fp16 WB) + head + softmax + mix (K-split partials) ----
__device__ __forceinline__ void stage_F2(
    int rowbase,
    const float* mlpA, const float* mlpB, const float* b1,
    const u16* WBpk, const float* b2,
    const float* W3, const float* b3,
    const float* lh, const float* lc,
    const float* ghp, const float* gcp,
    float* ghc, float* gcc)
{
  const int w = threadIdx.x >> 6, lane = threadIdx.x & 63;
  const int r0 = rowbase + w*2;
  const float* aA0 = mlpA + (size_t)r0*512; const float* aB0 = mlpB + (size_t)r0*512;
  const float* aA1 = aA0 + 512;             const float* aB1 = aB0 + 512;
  float m0[4] = {0.f,0.f,0.f,0.f}, m1[4] = {0.f,0.f,0.f,0.f};
  for (int k0 = 0; k0 < 512; k0 += 4) {
    float4 xa = *(const float4*)&aA0[k0];
    float4 xb = *(const float4*)&aB0[k0];
    float4 ya = *(const float4*)&aA1[k0];
    float4 yb = *(const float4*)&aB1[k0];
    float4 bb = *(const float4*)&b1[k0];
    float xv0[4] = { fmaxf(xa.x+xb.x+bb.x,0.f), fmaxf(xa.y+xb.y+bb.y,0.f),
                     fmaxf(xa.z+xb.z+bb.z,0.f), fmaxf(xa.w+xb.w+bb.w,0.f) };
    float xv1[4] = { fmaxf(ya.x+yb.x+bb.x,0.f), fmaxf(ya.y+yb.y+bb.y,0.f),
                     fmaxf(ya.z+yb.z+bb.z,0.f), fmaxf(ya.w+yb.w+bb.w,0.f) };
#pragma unroll
    for (int j = 0; j < 4; ++j) {
      f16x4 wv = *(const f16x4*)&WBpk[(size_t)(k0+j)*256 + lane*4];
      float w0 = (float)wv[0], w1 = (float)wv[1], w2 = (float)wv[2], w3v = (float)wv[3];
      m0[0] = __builtin_fmaf(xv0[j], w0, m0[0]);
      m0[1] = __builtin_fmaf(xv0[j], w1, m0[1]);
      m0[2] = __builtin_fmaf(xv0[j], w2, m0[2]);
      m0[3] = __builtin_fmaf(xv0[j], w3v, m0[3]);
      m1[0] = __builtin_fmaf(xv1[j], w0, m1[0]);
      m1[1] = __builtin_fmaf(xv1[j], w1, m1[1]);
      m1[2] = __builtin_fmaf(xv1[j], w2, m1[2]);
      m1[3] = __builtin_fmaf(xv1[j], w3v, m1[3]);
    }
  }
  float4 b = *(const float4*)&b2[lane*4];
  float bb2[4] = {b.x,b.y,b.z,b.w};
#pragma unroll
  for (int j = 0; j < 4; ++j) {
    m0[j] = fmaxf(m0[j]+bb2[j], 0.f);
    m1[j] = fmaxf(m1[j]+bb2[j], 0.f);
  }
  float4 w30 = *(const float4*)&W3[lane*4];
  float4 w31 = *(const float4*)&W3[256 + lane*4];
  float w0v[4] = {w30.x,w30.y,w30.z,w30.w};
  float w1v[4] = {w31.x,w31.y,w31.z,w31.w};
  float d00=0.f, d01=0.f, d10=0.f, d11=0.f;
#pragma unroll
  for (int j = 0; j < 4; ++j) {
    d00 = __builtin_fmaf(m0[j], w0v[j], d00);
    d01 = __builtin_fmaf(m0[j], w1v[j], d01);
    d10 = __builtin_fmaf(m1[j], w0v[j], d10);
    d11 = __builtin_fmaf(m1[j], w1v[j], d11);
  }
#pragma unroll
  for (int off = 32; off; off >>= 1) {
    d00 += __shfl_xor(d00, off, 64); d01 += __shfl_xor(d01, off, 64);
    d10 += __shfl_xor(d10, off, 64); d11 += __shfl_xor(d11, off, 64);
  }
  d00 += b3[0]; d01 += b3[1]; d10 += b3[0]; d11 += b3[1];
  float mxa = fmaxf(d00, d01), mxb = fmaxf(d10, d11);
  float e00 = __expf(d00-mxa), e01 = __expf(d01-mxa);
  float e10 = __expf(d10-mxb), e11 = __expf(d11-mxb);
  float ia = 1.f/(e00+e01), ib = 1.f/(e10+e11);
  float p0a = e00*ia, p1a = e01*ia;
  float p0b = e10*ib, p1b = e11*ib;
#pragma unroll
  for (int rr = 0; rr < 2; ++rr) {
    const float p0 = rr ? p0b : p0a, p1 = rr ? p1b : p1a;
    const size_t ix = (size_t)(r0+rr)*H_ + lane*4;
    float4 lv = *(const float4*)&lh[ix];
    float4 gv = *(const float4*)&ghp[ix];
    float4 o;
    o.x = p0*lv.x + p1*gv.x; o.y = p0*lv.y + p1*gv.y;
    o.z = p0*lv.z + p1*gv.z; o.w = p0*lv.w + p1*gv.w;
    *(float4*)&ghc[ix] = o;
    lv = *(const float4*)&lc[ix];
    gv = *(const float4*)&gcp[ix];
    o.x = p0*lv.x + p1*gv.x; o.y = p0*lv.y + p1*gv.y;
    o.z = p0*lv.z + p1*gv.z; o.w = p0*lv.w + p1*gv.w;
    *(float4*)&gcc[ix] = o;
  }
}

// -------- output projection, 16 rows per block (2 rows/wave) --------
__device__ __forceinline__ void stage_OUT2(
    const float* gh2c, const float* WOUT, const float* BOUT,
    float* out, int rbase, int tt)
{
  const int w = threadIdx.x >> 6, lane = threadIdx.x & 63;
  const bool two = lane < (V_ - 64);
#pragma unroll
  for (int rr = 0; rr < 2; ++rr) {
    const int r = rbase + w*2 + rr;
    const float* arow = gh2c + (size_t)r * H_;
    float acc0 = 0.f, acc1 = 0.f;
    for (int k0 = 0; k0 < 256; k0 += 4) {
      float4 a4 = *(const float4*)&arow[k0];
      float av[4] = {a4.x, a4.y, a4.z, a4.w};
#pragma unroll
      for (int j = 0; j < 4; ++j) {
        const float* wr_ = &WOUT[(size_t)(k0+j)*96];
        acc0 = __builtin_fmaf(av[j], wr_[lane], acc0);
        if (two) acc1 = __builtin_fmaf(av[j], wr_[64+lane], acc1);
      }
    }
    out[((size_t)r*V_ + lane)*T_ + tt] = acc0 + BOUT[lane];
    if (two) out[((size_t)r*V_ + 64 + lane)*T_ + tt] = acc1 + BOUT[64+lane];
  }
}

// ---------------- setup: zero states/bar, gather ex0, pack fp16 weights ----
__global__ void k_setup(InP in, float* __restrict__ ws)
{
  const size_t nthr = (size_t)gridDim.x * blockDim.x;
  const size_t t0 = (size_t)blockIdx.x * blockDim.x + threadIdx.x;

  for (size_t i = t0; i < 16*S_; i += nthr) ws[i] = 0.f;
  for (size_t i = t0; i < 8192; i += nthr) ((unsigned*)(ws + OFF_BAR))[i] = 0u;

  for (size_t i = t0; i < (size_t)B_*8; i += nthr) {
    int r = (int)(i >> 3), j = (int)(i & 7);
    ws[OFF_EX + i] = in.emb[(size_t)in.seq[(size_t)r*T_]*8 + j];
  }

  // WG1pk: [16 blk][8 ck][8 tiles][64 lane][8 e]; col = blk*128 + tile*16 + (lane&15)
  {
    u16* dst = (u16*)(ws + OFF_WG1PK);
    for (size_t i = t0; i < (size_t)16*8*8*512; i += nthr) {
      int e = (int)(i & 7), lane = (int)((i >> 3) & 63);
      int tile = (int)((i >> 9) & 7), ck = (int)((i >> 12) & 7), blk = (int)(i >> 15);
      int col = blk*128 + tile*16 + (lane & 15);
      int k = ck*32 + ((lane >> 4) << 3) + e;
      int cell = col >> 10, q = col & 1023;
      int h = ((q >> 6) << 4) + (q & 15), g = (q >> 4) & 3, R = g*256 + h;
      dst[i] = f2h((cell ? in.l1_Whh : in.g1_Whh)[(size_t)R*256 + k]);
    }
  }
  for (size_t i = t0; i < (size_t)8*2048; i += nthr) {
    int j = (int)(i >> 11), p = (int)(i & 2047);
    int cell = p >> 10, q = p & 1023;
    int h = ((q >> 6) << 4) + (q & 15), g = (q >> 4) & 3, R = g*256 + h;
    ws[OFF_WE1 + (size_t)j*2048 + p] = (cell ? in.l1_Wih : in.g1_Wih)[(size_t)R*8 + j];
  }
  for (size_t i = t0; i < 2048; i += nthr) {
    int p = (int)i, cell = p >> 10, q = p & 1023;
    int h = ((q >> 6) << 4) + (q & 15), g = (q >> 4) & 3, R = g*256 + h;
    ws[OFF_BG1 + i] = cell ? (in.l1_bih[R] + in.l1_bhh[R]) : (in.g1_bih[R] + in.g1_bhh[R]);
  }

  // WL2pk / WG2pk: [16 blk][16 ck][4 tiles][512]; col = blk*64 + tile*16 + (lane&15)
  for (int which = 0; which < 2; ++which) {
    u16* dst = (u16*)(ws + (which ? OFF_WG2PK : OFF_WL2PK));
    const float* Wih = which ? in.g2_Wih : in.l2_Wih;
    const float* Whh = which ? in.g2_Whh : in.l2_Whh;
    for (size_t i = t0; i < (size_t)16*16*4*512; i += nthr) {
      int e = (int)(i & 7), lane = (int)((i >> 3) & 63);
      int tile = (int)((i >> 9) & 3), ck = (int)((i >> 11) & 15), blk = (int)(i >> 15);
      int col = blk*64 + tile*16 + (lane & 15);
      int k = ck*32 + ((lane >> 4) << 3) + e;
      int h = ((col >> 6) << 4) + (col & 15), g = (col >> 4) & 3, R = g*256 + h;
      float w = (k < 256) ? Wih[(size_t)R*256 + k] : Whh[(size_t)R*256 + (k-256)];
      dst[i] = f2h(w);
    }
  }
  for (size_t i = t0; i < 2*1024; i += nthr) {
    int which = (int)(i >> 10), p = (int)(i & 1023);
    int h = ((p >> 6) << 4) + (p & 15), g = (p >> 4) & 3, R = g*256 + h;
    float v = which ? (in.g2_bih[R] + in.g2_bhh[R]) : (in.l2_bih[R] + in.l2_bhh[R]);
    ws[(which ? OFF_BG2 : OFF_BL2) + p] = v;
  }

  // WP1pk / WP2pk: [16 blk = kh*8+ct][16 ck][4 tiles][512]; col = ct*64 + tile*16 + (lane&15)
  for (int which = 0; which < 2; ++which) {
    u16* dst = (u16*)(ws + (which ? OFF_WP2PK : OFF_WP1PK));
    const float* W = which ? in.p2_W1 : in.p1_W1;
    for (size_t i = t0; i < (size_t)16*16*4*512; i += nthr) {
      int e = (int)(i & 7), lane = (int)((i >> 3) & 63);
      int tile = (int)((i >> 9) & 3), ck = (int)((i >> 11) & 15), blk = (int)(i >> 15);
      int kh = blk >> 3, ct = blk & 7;
      int col = ct*64 + tile*16 + (lane & 15);
      int k = kh*512 + ck*32 + ((lane >> 4) << 3) + e;
      dst[i] = f2h(W[(size_t)col*1032 + 8 + k]);
    }
  }
  for (size_t i = t0; i < (size_t)2*8*512; i += nthr) {
    int which = (int)(i / (8*512));
    int idx = (int)(i - (size_t)which*8*512);
    int j = idx >> 9, p = idx & 511;
    const float* W = which ? in.p2_W1 : in.p1_W1;
    ws[(which ? OFF_WEP2 : OFF_WEP1) + (size_t)j*512 + p] = W[(size_t)p*1032 + j];
  }

  // WB fp16 [512][256]
  for (size_t i = t0; i < (size_t)2*512*256; i += nthr) {
    int which = (int)(i / (512*256));
    int idx = (int)(i - (size_t)which*512*256);
    int k = idx >> 8, n = idx & 255;
    const float* W = which ? in.p2_W2 : in.p1_W2;
    ((u16*)(ws + (which ? OFF_WB2 : OFF_WB1)))[idx] = f2h(W[(size_t)n*512 + k]);
  }
  for (size_t i = t0; i < (size_t)256*96; i += nthr) {
    int k = (int)(i / 96), c = (int)(i - (size_t)k*96);
    float v = 0.f;
    if (c < V_) v = 0.5f*(in.gfc_W[(size_t)c*256 + k] + in.lfc_W[(size_t)c*256 + k]);
    ws[OFF_WOUT + i] = v;
  }
  for (size_t i = t0; i < 96; i += nthr)
    ws[OFF_BOUT + i] = (i < V_) ? 0.5f*(in.gfc_b[i] + in.lfc_b[i]) : 0.f;
}

// ------- main persistent kernel: 3-phase pipeline, DMA-prefetched weights -------
__global__ __launch_bounds__(NTHR) void k_main(InP in, float* ws, float* __restrict__ out)
{
  // occupancy pin: 24KB static pad + 64KB dynamic > 80KB -> 1 block/CU
  __shared__ __attribute__((aligned(16))) volatile float s_pad[6144];
  __shared__ unsigned s_slot;

  float* GH1C = ws + OFF_GH1C;  float* GC1C = ws + OFF_GC1C;
  float* GH1P = ws + OFF_GH1P;  float* GC1P = ws + OFF_GC1P;
  float* LH1  = ws + OFF_LH1;   float* LC1  = ws + OFF_LC1;
  float* GH2C = ws + OFF_GH2C;  float* GC2C = ws + OFF_GC2C;
  float* GH2P = ws + OFF_GH2P;  float* GC2P = ws + OFF_GC2P;
  float* LH2  = ws + OFF_LH2;   float* LC2  = ws + OFF_LC2;
  float* M1A  = ws + OFF_M1A;   float* M1B  = ws + OFF_M1B;
  float* M2A  = ws + OFF_M2A;   float* M2B  = ws + OFF_M2B;
  float* EXB  = ws + OFF_EX;
  const u16* WG1PK = (const u16*)(ws + OFF_WG1PK);
  const u16* WL2PK = (const u16*)(ws + OFF_WL2PK);
  const u16* WG2PK = (const u16*)(ws + OFF_WG2PK);
  const u16* WP1PK = (const u16*)(ws + OFF_WP1PK);
  const u16* WP2PK = (const u16*)(ws + OFF_WP2PK);
  const u16* WB1PK = (const u16*)(ws + OFF_WB1);
  const u16* WB2PK = (const u16*)(ws + OFF_WB2);
  const float* WE1  = ws + OFF_WE1;  const float* BG1P = ws + OFF_BG1;
  const float* BL2P = ws + OFF_BL2;  const float* BG2P = ws + OFF_BG2;
  const float* WEP1 = ws + OFF_WEP1; const float* WEP2 = ws + OFF_WEP2;
  const float* WOUT = ws + OFF_WOUT; const float* BOUT = ws + OFF_BOUT;

  unsigned xcc;
  asm volatile("s_getreg_b32 %0, hwreg(HW_REG_XCC_ID)" : "=s"(xcc));
  xcc &= 7u;
  unsigned* barx = ((unsigned*)(ws + OFF_BAR)) + xcc*1024;
  unsigned* arr  = barx;
  unsigned* reg  = barx + 544;
  if (threadIdx.x == 0) {
    s_slot = __hip_atomic_fetch_add(reg, 1u, __ATOMIC_RELAXED, __HIP_MEMORY_SCOPE_AGENT);
    s_pad[0] = (float)s_slot;     // keep static pad alive
  }
  __syncthreads();
  const int slot  = (int)(s_slot & 31u);
  const int rows0 = (int)xcc * 128;
  const int s2 = slot & 15;       // sub-index within half
  unsigned ep = 0;

  // prologue DMA: first P_A weights
  if (slot < 16) dma64(WG1PK + (size_t)slot*32768);
  else           dma64(WG2PK + (size_t)s2*32768);

  // cycle n: P_A gates1(n) || g2(n-1); P_B MLP1(n) || MLP2(n-1);
  //          P_C l2(n) || mix1(n)+ex(n+1) || mix2(n-1)+out(n-1)
  for (int n = 0; n <= T_; ++n) {
    const int sel = n & 1;
    const float* ex  = EXB + sel*(B_*8);
    const float* exm = EXB + (sel^1)*(B_*8);
    float* lh1o = LH1 + sel*S_;   float* lh1n = LH1 + (sel^1)*S_;
    float* lc1o = LC1 + sel*S_;   float* lc1n = LC1 + (sel^1)*S_;
    float* lh2o = LH2 + sel*S_;   float* lh2n = LH2 + (sel^1)*S_;
    float* lc2o = LC2 + sel*S_;   float* lc2n = LC2 + (sel^1)*S_;

    // ===== P_A =====
    if (slot < 16) {
      if (n < T_) {
        const int ct0 = slot*128;           // 128 cols, K=256
        const int cell = slot >> 3;
        GateEpiM<8> epi{ cell ? lc1o : GC1C,
                         cell ? lh1n : GH1P,
                         cell ? lc1n : GC1P,
                         BG1P, rows0, ct0 };
        mm_lds<8,1,true,8>(cell ? lh1o : GH1C, nullptr,
                           WE1, 2048, ex, rows0, ct0, epi);
      }
    } else if (n >= 1) {
      const int ct0 = s2*64;                // 64 cols, K=512
      GateEpiM<4> epi{ GC2C, GH2P, GC2P, BG2P, rows0, ct0 };
      mm_lds<16,2,false,4>(GH1C, GH2C, nullptr, 0, nullptr, rows0, ct0, epi);
    }
    __syncthreads();
    { // issue P_B weights (needed even at n==T_ for slots>=16)
      const int kh = s2 >> 3, ct = s2 & 7;
      const int blk = kh*8 + ct;
      if (slot < 16) dma64(WP1PK + (size_t)blk*32768);
      else           dma64(WP2PK + (size_t)blk*32768);
    }
    gbar_x(arr, slot, ++ep);

    // ===== P_B =====
    if (slot < 16) {
      if (n < T_) {
        const int kh = s2 >> 3, ct = s2 & 7;
        const int ct0 = ct*64;
        if (kh == 0) {
          MlpEpiM epi{ M1A, rows0, ct0 };
          mm_lds<16,2,false,4>(GH1P, GC1P, nullptr, 0, nullptr, rows0, ct0, epi);
        } else {
          MlpEpiM epi{ M1B, rows0, ct0 };
          mm_lds<16,2,true,4>(lh1n, lc1n, WEP1, 512, ex, rows0, ct0, epi);
        }
      }
    } else if (n >= 1) {
      const int kh = s2 >> 3, ct = s2 & 7;
      const int ct0 = ct*64;
      if (kh == 0) {
        MlpEpiM epi{ M2A, rows0, ct0 };
        mm_lds<16,2,false,4>(GH2P, GC2P, nullptr, 0, nullptr, rows0, ct0, epi);
      } else {
        MlpEpiM epi{ M2B, rows0, ct0 };
        mm_lds<16,2,true,4>(lh2o, lc2o, WEP2, 512, exm, rows0, ct0, epi);
      }
    }
    __syncthreads();
    if (n < T_) { // issue P_C / next P_A weights
      if (slot < 16) dma64(WL2PK + (size_t)slot*32768);       // l2 this cycle
      else           dma64(WG2PK + (size_t)s2*32768);          // g2 next cycle
    }
    gbar_x(arr, slot, ++ep);

    // ===== P_C =====
    if (slot < 16) {
      if (n < T_) {
        const int ct0 = slot*64;              // 64 cols, K=512
        GateEpiM<4> epi{ lc2o, lh2n, lc2n, BL2P, rows0, ct0 };
        mm_lds<16,2,false,4>(lh1n, lh2o, nullptr, 0, nullptr, rows0, ct0, epi);
      }
    } else if (slot < 24) {
      if (n < T_) {
        const int rb = rows0 + (slot-16)*16;
        stage_F2(rb, M1A, M1B, in.p1_b1, WB1PK, in.p1_b2, in.p1_W3, in.p1_b3,
                 lh1n, lc1n, GH1P, GC1P, GH1C, GC1C);
        if (n + 1 < T_ && threadIdx.x < 128) {
          const int r = rb + (threadIdx.x >> 3), j = threadIdx.x & 7;
          EXB[(sel^1)*(B_*8) + r*8 + j] =
              in.emb[(size_t)in.seq[(size_t)r*T_ + n + 1]*8 + j];
        }
      }
    } else {
      if (n >= 1) {
        const int rb = rows0 + (slot-24)*16;
        stage_F2(rb, M2A, M2B, in.p2_b1, WB2PK, in.p2_b2, in.p2_W3, in.p2_b3,
                 lh2o, lc2o, GH2P, GC2P, GH2C, GC2C);
        __syncthreads();
        stage_OUT2(GH2C, WOUT, BOUT, out, rb, n-1);
      }
    }
    __syncthreads();
    if (n < T_ - 1) {  // issue next cycle's P_A weights (gates1) for slots<16
      if (slot < 16) dma64(WG1PK + (size_t)slot*32768);
    }
    gbar_x(arr, slot, ++ep);
  }
}

// ---------------- host ----------------
extern "C" void kernel_launch(void* const* d_in, const int* in_sizes, int n_in,
                              void* d_out, int out_size, void* d_ws, size_t ws_size,
                              hipStream_t stream)
{
  if (ws_size < WS_FLOATS * sizeof(float)) return;

  InP in;
  in.seq    = (const int*)  d_in[0];
  in.emb    = (const float*)d_in[1];
  in.g1_Wih = (const float*)d_in[2];  in.g1_Whh = (const float*)d_in[3];
  in.g1_bih = (const float*)d_in[4];  in.g1_bhh = (const float*)d_in[5];
  in.g2_Wih = (const float*)d_in[6];  in.g2_Whh = (const float*)d_in[7];
  in.g2_bih = (const float*)d_in[8];  in.g2_bhh = (const float*)d_in[9];
  in.l1_Wih = (const float*)d_in[10]; in.l1_Whh = (const float*)d_in[11];
  in.l1_bih = (const float*)d_in[12]; in.l1_bhh = (const float*)d_in[13];
  in.l2_Wih = (const float*)d_in[14]; in.l2_Whh = (const float*)d_in[15];
  in.l2_bih = (const float*)d_in[16]; in.l2_bhh = (const float*)d_in[17];
  in.p1_W1  = (const float*)d_in[18]; in.p1_b1  = (const float*)d_in[19];
  in.p1_W2  = (const float*)d_in[20]; in.p1_b2  = (const float*)d_in[21];
  in.p1_W3  = (const float*)d_in[22]; in.p1_b3  = (const float*)d_in[23];
  in.p2_W1  = (const float*)d_in[24]; in.p2_b1  = (const float*)d_in[25];
  in.p2_W2  = (const float*)d_in[26]; in.p2_b2  = (const float*)d_in[27];
  in.p2_W3  = (const float*)d_in[28]; in.p2_b3  = (const float*)d_in[29];
  in.gfc_W  = (const float*)d_in[30]; in.gfc_b  = (const float*)d_in[31];
  in.lfc_W  = (const float*)d_in[32]; in.lfc_b  = (const float*)d_in[33];

  float* ws  = (float*)d_ws;
  float* out = (float*)d_out;

  k_setup<<<512, 256, 0, stream>>>(in, ws);
  k_main <<<NBLK, NTHR, 65536, stream>>>(in, ws, out);   // 64KB dyn LDS (B tiles)
}

// Round 12
// 57611.255 us; speedup vs baseline: 1.4243x; 1.1761x over previous
//
#include <hip/hip_runtime.h>

#define B_ 1024
#define T_ 256
#define V_ 90
#define H_ 256
#define NTHR 512
#define NBLK 256
#define S_ ((size_t)B_*H_)

typedef unsigned short u16;
typedef __attribute__((ext_vector_type(8))) _Float16 f16x8;
typedef __attribute__((ext_vector_type(4))) _Float16 f16x4;
typedef __attribute__((ext_vector_type(4))) float f32x4;

// ---------------- ws layout (float offsets) ----------------
constexpr size_t OFF_GH1C  = 0;
constexpr size_t OFF_GC1C  = OFF_GH1C + S_;
constexpr size_t OFF_GH1P  = OFF_GC1C + S_;
constexpr size_t OFF_GC1P  = OFF_GH1P + S_;
constexpr size_t OFF_LH1   = OFF_GC1P + S_;      // 2 buffers
constexpr size_t OFF_LC1   = OFF_LH1 + 2*S_;
constexpr size_t OFF_GH2C  = OFF_LC1 + 2*S_;
constexpr size_t OFF_GC2C  = OFF_GH2C + S_;
constexpr size_t OFF_GH2P  = OFF_GC2C + S_;
constexpr size_t OFF_GC2P  = OFF_GH2P + S_;
constexpr size_t OFF_LH2   = OFF_GC2P + S_;      // 2 buffers
constexpr size_t OFF_LC2   = OFF_LH2 + 2*S_;
constexpr size_t OFF_M1H   = OFF_LC2 + 2*S_;     // fp16 [B][512] (post-ReLU)
constexpr size_t OFF_M2H   = OFF_M1H + (size_t)B_*512/2;
constexpr size_t OFF_OSTG  = OFF_M2H + (size_t)B_*512/2;  // [B][16][90] fp32
constexpr size_t OFF_EX    = OFF_OSTG + (size_t)B_*16*90; // 2*1024*8
// fp16 packed weights, per-block-contiguous 64KB slices
constexpr size_t OFF_WG1PK = OFF_EX + 2*B_*8;            // 16 blk x 32768 u16
constexpr size_t OFF_WE1   = OFF_WG1PK + 256*2048/2;     // fp32 [8][2048pk]
constexpr size_t OFF_BG1   = OFF_WE1 + 8*2048;
constexpr size_t OFF_WL2PK = OFF_BG1 + 2048;             // 16 blk x 32768 u16
constexpr size_t OFF_BL2   = OFF_WL2PK + 512*1024/2;
constexpr size_t OFF_WG2PK = OFF_BL2 + 1024;
constexpr size_t OFF_BG2   = OFF_WG2PK + 512*1024/2;
constexpr size_t OFF_WP1PK = OFF_BG2 + 1024;             // 16 blk x 32768 u16
constexpr size_t OFF_WEP1  = OFF_WP1PK + 1024*512/2;
constexpr size_t OFF_WP2PK = OFF_WEP1 + 8*512;
constexpr size_t OFF_WEP2  = OFF_WP2PK + 1024*512/2;
constexpr size_t OFF_WB1   = OFF_WEP2 + 8*512;           // fp16 [512][256]
constexpr size_t OFF_WB2   = OFF_WB1 + 512*256/2;
constexpr size_t OFF_WOUT  = OFF_WB2 + 512*256/2;        // fp32 [256][96]
constexpr size_t OFF_BOUT  = OFF_WOUT + 256*96;
constexpr size_t OFF_BAR   = OFF_BOUT + 128;             // 8 XCD * 1024 uints
constexpr size_t WS_FLOATS = OFF_BAR + 8192;

struct InP {
  const int*   seq;
  const float* emb;
  const float *g1_Wih,*g1_Whh,*g1_bih,*g1_bhh;
  const float *g2_Wih,*g2_Whh,*g2_bih,*g2_bhh;
  const float *l1_Wih,*l1_Whh,*l1_bih,*l1_bhh;
  const float *l2_Wih,*l2_Whh,*l2_bih,*l2_bhh;
  const float *p1_W1,*p1_b1,*p1_W2,*p1_b2,*p1_W3,*p1_b3;
  const float *p2_W1,*p2_b1,*p2_W2,*p2_b2,*p2_W3,*p2_b3;
  const float *gfc_W,*gfc_b,*lfc_W,*lfc_b;
};

__device__ __forceinline__ float sig_(float x)  { return 1.f/(1.f+__expf(-x)); }
__device__ __forceinline__ float tanh_(float x) { return 1.f - 2.f/(__expf(2.f*x)+1.f); }
__device__ __forceinline__ u16 f2h(float v) {
  _Float16 h = (_Float16)v; return __builtin_bit_cast(unsigned short, h);
}

// ---- AGENT-scope (sc1) flag ops (R7-proven) ----
__device__ __forceinline__ unsigned ld_flag(const unsigned* p) {
  unsigned v;
  asm volatile("global_load_dword %0, %1, off sc1\n\ts_waitcnt vmcnt(0)"
               : "=v"(v) : "v"(p) : "memory");
  return v;
}
__device__ __forceinline__ void st_flag(unsigned* p, unsigned v) {
  asm volatile("global_store_dword %0, %1, off sc1\n\ts_waitcnt vmcnt(0)"
               :: "v"(p), "v"(v) : "memory");
}

// -------- per-XCD barrier: all-poll epoch flags (R9-proven) --------
__device__ __forceinline__ void gbar_x(unsigned* arr, int slot, unsigned ep)
{
  __syncthreads();                       // drains vmcnt(0): stores + DMA in L2/LDS
  if (threadIdx.x == 0) st_flag(&arr[slot*16], ep);
  if (threadIdx.x < 32) {
    int cap = 0;
    for (;;) {
      unsigned v = ld_flag(&arr[threadIdx.x*16]);
      if (v >= ep) break;
      __builtin_amdgcn_s_sleep(1);
      if (++cap > 200000) break;
    }
  }
  __syncthreads();
  asm volatile("buffer_inv sc0" ::: "memory");   // vL1 invalidate only
}

// -------- async weight DMA: 64KB contiguous global -> dynamic LDS --------
// aux=2 (NT): evict-first in L2 so the weight stream doesn't flush hot state.
__device__ __forceinline__ void gl_lds16(const void* g, void* l) {
  __builtin_amdgcn_global_load_lds(
      (const __attribute__((address_space(1))) unsigned int*)g,
      (__attribute__((address_space(3))) unsigned int*)l, 16, 0, 2);
}
__device__ __forceinline__ void dma64(const u16* src) {
  extern __shared__ u16 dynB[];
  const int wv = threadIdx.x >> 6, lane = threadIdx.x & 63;
  const char* g = (const char*)src + lane*16;
  char* l = (char*)dynB;
#pragma unroll
  for (int j = 0; j < 8; ++j) {
    const int ofs = (wv*8 + j) * 1024;     // 8 waves x 8KB = 64KB
    gl_lds16(g + ofs, l + ofs);
  }
}

// ====== fp16 MFMA tile GEMM: 128 rows x (TPW*16) cols, 8 row-wave-strips ======
// B pre-DMA'd into dynB (drained at the preceding gbar -> no entry sync needed).
// A: per-lane direct global (8 fp32), depth-4 register ring, NO syncs in loop.
// A frag: lane&15 = row, k = (lane>>4)*8 + e.  C/D: col=l&15, row=(l>>4)*4+reg.
template<int NCH, int NSEG, bool HASE, int TPW, class FE>
__device__ __forceinline__ void mm_lds(
    const float* s0, const float* s1_, const float* s2_, const float* s3_,
    const float* WeP, int ldwe, const float* ex,
    int rows0, int ct0, FE fe)
{
  extern __shared__ u16 dynB[];
  const int tid = threadIdx.x, lane = tid & 63, wr = tid >> 6;
  const int row = rows0 + wr*16 + (lane & 15);
  const int kq  = (lane >> 4) << 3;

  f32x4 acc[TPW];
#pragma unroll
  for (int t = 0; t < TPW; ++t) acc[t] = (f32x4){0,0,0,0};

  float4 alo[4], ahi[4];
  auto ldA = [&](int c, float4& lo, float4& hi) {
    const int k0 = c * 32;
    const float* S;
    if (NSEG == 1) S = s0;
    else if (NSEG == 2) S = (k0 < 256) ? s0 : s1_;
    else S = (k0 < 256) ? s0 : (k0 < 512) ? s1_ : (k0 < 768) ? s2_ : s3_;
    const float* p = &S[(size_t)row*H_ + (k0 & 255) + kq];
    lo = *(const float4*)p; hi = *(const float4*)(p + 4);
  };
  auto comp = [&](int c, const float4& lo, const float4& hi) {
    float av[8] = {lo.x,lo.y,lo.z,lo.w,hi.x,hi.y,hi.z,hi.w};
    f16x8 a;
#pragma unroll
    for (int j = 0; j < 8; ++j) a[j] = (_Float16)av[j];
#pragma unroll
    for (int t = 0; t < TPW; ++t) {
      f16x8 b = *(const f16x8*)(dynB + (size_t)(c*TPW + t)*512 + lane*8);
      acc[t] = __builtin_amdgcn_mfma_f32_16x16x32_f16(a, b, acc[t], 0, 0, 0);
    }
  };

#pragma unroll
  for (int c = 0; c < 4; ++c) ldA(c, alo[c], ahi[c]);
#pragma unroll
  for (int c = 0; c < NCH; ++c) {
    comp(c, alo[c & 3], ahi[c & 3]);
    if (c + 4 < NCH) ldA(c + 4, alo[c & 3], ahi[c & 3]);
  }

  if (HASE) {   // E-correction (K=8 embedding part), L2-resident reads
#pragma unroll
    for (int t = 0; t < TPW; ++t) {
      const int colL = ct0 + t*16 + (lane & 15);
      float w[8];
#pragma unroll
      for (int j = 0; j < 8; ++j) w[j] = WeP[j*ldwe + colL];
#pragma unroll
      for (int m = 0; m < 4; ++m) {
        const int rr = rows0 + wr*16 + ((lane >> 4) << 2) + m;
        float s = 0.f;
#pragma unroll
        for (int j = 0; j < 8; ++j) s = __builtin_fmaf(ex[rr*8 + j], w[j], s);
        acc[t][m] += s;
      }
    }
  }
  fe(wr, lane, acc);
}

// ---------------- MFMA epilogues ----------------
template<int TPW>
struct GateEpiM {
  const float* cin; float* ho; float* co; const float* bias_pk;
  int rows0; int ct0;
  __device__ void operator()(int wr, int lane, f32x4 (&acc)[TPW]) const {
    const int rbase = rows0 + wr*16 + ((lane >> 4) << 2);
#pragma unroll
    for (int gi = 0; gi < TPW/4; ++gi) {
      const int cb = ct0 + gi*64;
      const int h = (((cb & 1023) >> 6) << 4) + (lane & 15);
      float b[4];
#pragma unroll
      for (int t = 0; t < 4; ++t) b[t] = bias_pk[cb + t*16 + (lane & 15)];
#pragma unroll
      for (int m = 0; m < 4; ++m) {
        const size_t ix = (size_t)(rbase + m)*H_ + h;
        float gI = sig_(acc[gi*4+0][m] + b[0]);
        float gF = sig_(acc[gi*4+1][m] + b[1]);
        float gG = tanh_(acc[gi*4+2][m] + b[2]);
        float gO = sig_(acc[gi*4+3][m] + b[3]);
        float cn = gF*cin[ix] + gI*gG;
        ho[ix] = gO*tanh_(cn); co[ix] = cn;
      }
    }
  }
};

// MLP epilogue: bias + ReLU, store fp16 (full-K sum, no partials)
struct MlpEpiH {
  u16* dst; const float* b1; int rows0; int ct0;
  __device__ void operator()(int wr, int lane, f32x4 (&acc)[2]) const {
    const int rbase = rows0 + wr*16 + ((lane >> 4) << 2);
#pragma unroll
    for (int t = 0; t < 2; ++t) {
      const int c = ct0 + t*16 + (lane & 15);
      const float bb = b1[c];
#pragma unroll
      for (int m = 0; m < 4; ++m)
        dst[(size_t)(rbase + m)*512 + c] = f2h(fmaxf(acc[t][m] + bb, 0.f));
    }
  }
};

// ---- fused p-MLP2(fp16 M, fp16 WB) + head + softmax + mix ----
__device__ __forceinline__ void stage_F2(
    int rowbase,
    const u16* M, const u16* WBpk, const float* b2,
    const float* W3, const float* b3,
    const float* lh, const float* lc,
    const float* ghp, const float* gcp,
    float* ghc, float* gcc)
{
  const int w = threadIdx.x >> 6, lane = threadIdx.x & 63;
  const int r0 = rowbase + w*2;
  const u16* a0 = M + (size_t)r0*512;
  const u16* a1 = a0 + 512;
  float m0[4] = {0.f,0.f,0.f,0.f}, m1[4] = {0.f,0.f,0.f,0.f};
  for (int k0 = 0; k0 < 512; k0 += 4) {
    f16x4 x0 = *(const f16x4*)&a0[k0];
    f16x4 x1 = *(const f16x4*)&a1[k0];
#pragma unroll
    for (int j = 0; j < 4; ++j) {
      f16x4 wv = *(const f16x4*)&WBpk[(size_t)(k0+j)*256 + lane*4];
      float w0 = (float)wv[0], w1 = (float)wv[1], w2 = (float)wv[2], w3v = (float)wv[3];
      float xv0 = (float)x0[j], xv1 = (float)x1[j];
      m0[0] = __builtin_fmaf(xv0, w0, m0[0]);
      m0[1] = __builtin_fmaf(xv0, w1, m0[1]);
      m0[2] = __builtin_fmaf(xv0, w2, m0[2]);
      m0[3] = __builtin_fmaf(xv0, w3v, m0[3]);
      m1[0] = __builtin_fmaf(xv1, w0, m1[0]);
      m1[1] = __builtin_fmaf(xv1, w1, m1[1]);
      m1[2] = __builtin_fmaf(xv1, w2, m1[2]);
      m1[3] = __builtin_fmaf(xv1, w3v, m1[3]);
    }
  }
  float4 b = *(const float4*)&b2[lane*4];
  float bb2[4] = {b.x,b.y,b.z,b.w};
#pragma unroll
  for (int j = 0; j < 4; ++j) {
    m0[j] = fmaxf(m0[j]+bb2[j], 0.f);
    m1[j] = fmaxf(m1[j]+bb2[j], 0.f);
  }
  float4 w30 = *(const float4*)&W3[lane*4];
  float4 w31 = *(const float4*)&W3[256 + lane*4];
  float w0v[4] = {w30.x,w30.y,w30.z,w30.w};
  float w1v[4] = {w31.x,w31.y,w31.z,w31.w};
  float d00=0.f, d01=0.f, d10=0.f, d11=0.f;
#pragma unroll
  for (int j = 0; j < 4; ++j) {
    d00 = __builtin_fmaf(m0[j], w0v[j], d00);
    d01 = __builtin_fmaf(m0[j], w1v[j], d01);
    d10 = __builtin_fmaf(m1[j], w0v[j], d10);
    d11 = __builtin_fmaf(m1[j], w1v[j], d11);
  }
#pragma unroll
  for (int off = 32; off; off >>= 1) {
    d00 += __shfl_xor(d00, off, 64); d01 += __shfl_xor(d01, off, 64);
    d10 += __shfl_xor(d10, off, 64); d11 += __shfl_xor(d11, off, 64);
  }
  d00 += b3[0]; d01 += b3[1]; d10 += b3[0]; d11 += b3[1];
  float mxa = fmaxf(d00, d01), mxb = fmaxf(d10, d11);
  float e00 = __expf(d00-mxa), e01 = __expf(d01-mxa);
  float e10 = __expf(d10-mxb), e11 = __expf(d11-mxb);
  float ia = 1.f/(e00+e01), ib = 1.f/(e10+e11);
  float p0a = e00*ia, p1a = e01*ia;
  float p0b = e10*ib, p1b = e11*ib;
#pragma unroll
  for (int rr = 0; rr < 2; ++rr) {
    const float p0 = rr ? p0b : p0a, p1 = rr ? p1b : p1a;
    const size_t ix = (size_t)(r0+rr)*H_ + lane*4;
    float4 lv = *(const float4*)&lh[ix];
    float4 gv = *(const float4*)&ghp[ix];
    float4 o;
    o.x = p0*lv.x + p1*gv.x; o.y = p0*lv.y + p1*gv.y;
    o.z = p0*lv.z + p1*gv.z; o.w = p0*lv.w + p1*gv.w;
    *(float4*)&ghc[ix] = o;
    lv = *(const float4*)&lc[ix];
    gv = *(const float4*)&gcp[ix];
    o.x = p0*lv.x + p1*gv.x; o.y = p0*lv.y + p1*gv.y;
    o.z = p0*lv.z + p1*gv.z; o.w = p0*lv.w + p1*gv.w;
    *(float4*)&gcc[ix] = o;
  }
}

// -------- output projection -> staging buffer [r][t&15][90] (coalesced) --------
__device__ __forceinline__ void stage_OUTS(
    const float* gh2c, const float* WOUT, const float* BOUT,
    float* ostg, int rbase, int tt)
{
  const int w = threadIdx.x >> 6, lane = threadIdx.x & 63;
  const bool two = lane < (V_ - 64);
#pragma unroll
  for (int rr = 0; rr < 2; ++rr) {
    const int r = rbase + w*2 + rr;
    const float* arow = gh2c + (size_t)r * H_;
    float acc0 = 0.f, acc1 = 0.f;
    for (int k0 = 0; k0 < 256; k0 += 4) {
      float4 a4 = *(const float4*)&arow[k0];
      float av[4] = {a4.x, a4.y, a4.z, a4.w};
#pragma unroll
      for (int j = 0; j < 4; ++j) {
        const float* wr_ = &WOUT[(size_t)(k0+j)*96];
        acc0 = __builtin_fmaf(av[j], wr_[lane], acc0);
        if (two) acc1 = __builtin_fmaf(av[j], wr_[64+lane], acc1);
      }
    }
    float* dst = &ostg[((size_t)r*16 + (tt & 15))*90];
    if (lane < 64) dst[lane] = acc0 + BOUT[lane];
    if (two) dst[64+lane] = acc1 + BOUT[64+lane];
  }
}

// -------- flush 16 t-columns: full-line 64B writes to out --------
__device__ __forceinline__ void flush_out(
    const float* ostg, float* out, int rbase, int tb0)
{
  for (int i = threadIdx.x; i < 16*90; i += NTHR) {
    const int rr = i / 90, v = i - rr*90;
    const int r = rbase + rr;
    const float* src = &ostg[((size_t)r*16)*90 + v];
    float tmp[16];
#pragma unroll
    for (int tb = 0; tb < 16; ++tb) tmp[tb] = src[tb*90];
    float* dst = &out[((size_t)r*V_ + v)*T_ + tb0];
#pragma unroll
    for (int q = 0; q < 4; ++q)
      ((float4*)dst)[q] = make_float4(tmp[q*4], tmp[q*4+1], tmp[q*4+2], tmp[q*4+3]);
  }
}

// ---------------- setup: zero states/bar, gather ex0, pack fp16 weights ----
__global__ void k_setup(InP in, float* __restrict__ ws)
{
  const size_t nthr = (size_t)gridDim.x * blockDim.x;
  const size_t t0 = (size_t)blockIdx.x * blockDim.x + threadIdx.x;

  for (size_t i = t0; i < 16*S_; i += nthr) ws[i] = 0.f;
  for (size_t i = t0; i < 8192; i += nthr) ((unsigned*)(ws + OFF_BAR))[i] = 0u;

  for (size_t i = t0; i < (size_t)B_*8; i += nthr) {
    int r = (int)(i >> 3), j = (int)(i & 7);
    ws[OFF_EX + i] = in.emb[(size_t)in.seq[(size_t)r*T_]*8 + j];
  }

  // WG1pk: [16 blk][8 ck][8 tiles][64 lane][8 e]; col = blk*128 + tile*16 + (lane&15)
  {
    u16* dst = (u16*)(ws + OFF_WG1PK);
    for (size_t i = t0; i < (size_t)16*8*8*512; i += nthr) {
      int e = (int)(i & 7), lane = (int)((i >> 3) & 63);
      int tile = (int)((i >> 9) & 7), ck = (int)((i >> 12) & 7), blk = (int)(i >> 15);
      int col = blk*128 + tile*16 + (lane & 15);
      int k = ck*32 + ((lane >> 4) << 3) + e;
      int cell = col >> 10, q = col & 1023;
      int h = ((q >> 6) << 4) + (q & 15), g = (q >> 4) & 3, R = g*256 + h;
      dst[i] = f2h((cell ? in.l1_Whh : in.g1_Whh)[(size_t)R*256 + k]);
    }
  }
  for (size_t i = t0; i < (size_t)8*2048; i += nthr) {
    int j = (int)(i >> 11), p = (int)(i & 2047);
    int cell = p >> 10, q = p & 1023;
    int h = ((q >> 6) << 4) + (q & 15), g = (q >> 4) & 3, R = g*256 + h;
    ws[OFF_WE1 + (size_t)j*2048 + p] = (cell ? in.l1_Wih : in.g1_Wih)[(size_t)R*8 + j];
  }
  for (size_t i = t0; i < 2048; i += nthr) {
    int p = (int)i, cell = p >> 10, q = p & 1023;
    int h = ((q >> 6) << 4) + (q & 15), g = (q >> 4) & 3, R = g*256 + h;
    ws[OFF_BG1 + i] = cell ? (in.l1_bih[R] + in.l1_bhh[R]) : (in.g1_bih[R] + in.g1_bhh[R]);
  }

  // WL2pk / WG2pk: [16 blk][16 ck][4 tiles][512]; col = blk*64 + tile*16 + (lane&15)
  for (int which = 0; which < 2; ++which) {
    u16* dst = (u16*)(ws + (which ? OFF_WG2PK : OFF_WL2PK));
    const float* Wih = which ? in.g2_Wih : in.l2_Wih;
    const float* Whh = which ? in.g2_Whh : in.l2_Whh;
    for (size_t i = t0; i < (size_t)16*16*4*512; i += nthr) {
      int e = (int)(i & 7), lane = (int)((i >> 3) & 63);
      int tile = (int)((i >> 9) & 3), ck = (int)((i >> 11) & 15), blk = (int)(i >> 15);
      int col = blk*64 + tile*16 + (lane & 15);
      int k = ck*32 + ((lane >> 4) << 3) + e;
      int h = ((col >> 6) << 4) + (col & 15), g = (col >> 4) & 3, R = g*256 + h;
      float w = (k < 256) ? Wih[(size_t)R*256 + k] : Whh[(size_t)R*256 + (k-256)];
      dst[i] = f2h(w);
    }
  }
  for (size_t i = t0; i < 2*1024; i += nthr) {
    int which = (int)(i >> 10), p = (int)(i & 1023);
    int h = ((p >> 6) << 4) + (p & 15), g = (p >> 4) & 3, R = g*256 + h;
    float v = which ? (in.g2_bih[R] + in.g2_bhh[R]) : (in.l2_bih[R] + in.l2_bhh[R]);
    ws[(which ? OFF_BG2 : OFF_BL2) + p] = v;
  }

  // WP1pk / WP2pk: [16 blk][32 ck][2 tiles][512]; col = blk*32 + tile*16 + (lane&15)
  for (int which = 0; which < 2; ++which) {
    u16* dst = (u16*)(ws + (which ? OFF_WP2PK : OFF_WP1PK));
    const float* W = which ? in.p2_W1 : in.p1_W1;
    for (size_t i = t0; i < (size_t)16*32*2*512; i += nthr) {
      int e = (int)(i & 7), lane = (int)((i >> 3) & 63);
      int tile = (int)((i >> 9) & 1), ck = (int)((i >> 10) & 31), blk = (int)(i >> 15);
      int col = blk*32 + tile*16 + (lane & 15);
      int k = ck*32 + ((lane >> 4) << 3) + e;
      dst[i] = f2h(W[(size_t)col*1032 + 8 + k]);
    }
  }
  for (size_t i = t0; i < (size_t)2*8*512; i += nthr) {
    int which = (int)(i / (8*512));
    int idx = (int)(i - (size_t)which*8*512);
    int j = idx >> 9, p = idx & 511;
    const float* W = which ? in.p2_W1 : in.p1_W1;
    ws[(which ? OFF_WEP2 : OFF_WEP1) + (size_t)j*512 + p] = W[(size_t)p*1032 + j];
  }

  // WB fp16 [512][256]
  for (size_t i = t0; i < (size_t)2*512*256; i += nthr) {
    int which = (int)(i / (512*256));
    int idx = (int)(i - (size_t)which*512*256);
    int k = idx >> 8, n = idx & 255;
    const float* W = which ? in.p2_W2 : in.p1_W2;
    ((u16*)(ws + (which ? OFF_WB2 : OFF_WB1)))[idx] = f2h(W[(size_t)n*512 + k]);
  }
  for (size_t i = t0; i < (size_t)256*96; i += nthr) {
    int k = (int)(i / 96), c = (int)(i - (size_t)k*96);
    float v = 0.f;
    if (c < V_) v = 0.5f*(in.gfc_W[(size_t)c*256 + k] + in.lfc_W[(size_t)c*256 + k]);
    ws[OFF_WOUT + i] = v;
  }
  for (size_t i = t0; i < 96; i += nthr)
    ws[OFF_BOUT + i] = (i < V_) ? 0.5f*(in.gfc_b[i] + in.lfc_b[i]) : 0.f;
}

// ------- main persistent kernel: 3-phase pipeline, NT-DMA weights, L2-hot state -------
__global__ __launch_bounds__(NTHR) void k_main(InP in, float* ws, float* __restrict__ out)
{
  // occupancy pin: 24KB static pad + 64KB dynamic > 80KB -> 1 block/CU
  __shared__ __attribute__((aligned(16))) volatile float s_pad[6144];
  __shared__ unsigned s_slot;

  float* GH1C = ws + OFF_GH1C;  float* GC1C = ws + OFF_GC1C;
  float* GH1P = ws + OFF_GH1P;  float* GC1P = ws + OFF_GC1P;
  float* LH1  = ws + OFF_LH1;   float* LC1  = ws + OFF_LC1;
  float* GH2C = ws + OFF_GH2C;  float* GC2C = ws + OFF_GC2C;
  float* GH2P = ws + OFF_GH2P;  float* GC2P = ws + OFF_GC2P;
  float* LH2  = ws + OFF_LH2;   float* LC2  = ws + OFF_LC2;
  u16*   M1H  = (u16*)(ws + OFF_M1H);
  u16*   M2H  = (u16*)(ws + OFF_M2H);
  float* OSTG = ws + OFF_OSTG;
  float* EXB  = ws + OFF_EX;
  const u16* WG1PK = (const u16*)(ws + OFF_WG1PK);
  const u16* WL2PK = (const u16*)(ws + OFF_WL2PK);
  const u16* WG2PK = (const u16*)(ws + OFF_WG2PK);
  const u16* WP1PK = (const u16*)(ws + OFF_WP1PK);
  const u16* WP2PK = (const u16*)(ws + OFF_WP2PK);
  const u16* WB1PK = (const u16*)(ws + OFF_WB1);
  const u16* WB2PK = (const u16*)(ws + OFF_WB2);
  const float* WE1  = ws + OFF_WE1;  const float* BG1P = ws + OFF_BG1;
  const float* BL2P = ws + OFF_BL2;  const float* BG2P = ws + OFF_BG2;
  const float* WEP1 = ws + OFF_WEP1; const float* WEP2 = ws + OFF_WEP2;
  const float* WOUT = ws + OFF_WOUT; const float* BOUT = ws + OFF_BOUT;

  unsigned xcc;
  asm volatile("s_getreg_b32 %0, hwreg(HW_REG_XCC_ID)" : "=s"(xcc));
  xcc &= 7u;
  unsigned* barx = ((unsigned*)(ws + OFF_BAR)) + xcc*1024;
  unsigned* arr  = barx;
  unsigned* reg  = barx + 544;
  if (threadIdx.x == 0) {
    s_slot = __hip_atomic_fetch_add(reg, 1u, __ATOMIC_RELAXED, __HIP_MEMORY_SCOPE_AGENT);
    s_pad[0] = (float)s_slot;     // keep static pad alive
  }
  __syncthreads();
  const int slot  = (int)(s_slot & 31u);
  const int rows0 = (int)xcc * 128;
  const int s2 = slot & 15;
  unsigned ep = 0;

  // prologue DMA: first P_A weights; drain before loop
  if (slot < 16) dma64(WG1PK + (size_t)slot*32768);
  else           dma64(WG2PK + (size_t)s2*32768);
  asm volatile("s_waitcnt vmcnt(0)" ::: "memory");
  __syncthreads();

  // cycle n: P_A gates1(n) || g2(n-1); P_B MLP1(n) || MLP2(n-1);
  //          P_C l2(n) || mix1(n)+ex(n+1) || mix2(n-1)+out-stage(n-1)
  for (int n = 0; n <= T_; ++n) {
    const int sel = n & 1;
    const float* ex  = EXB + sel*(B_*8);
    const float* exm = EXB + (sel^1)*(B_*8);
    float* lh1o = LH1 + sel*S_;   float* lh1n = LH1 + (sel^1)*S_;
    float* lc1o = LC1 + sel*S_;   float* lc1n = LC1 + (sel^1)*S_;
    float* lh2o = LH2 + sel*S_;   float* lh2n = LH2 + (sel^1)*S_;
    float* lc2o = LC2 + sel*S_;   float* lc2n = LC2 + (sel^1)*S_;

    // ===== P_A =====
    if (slot < 16) {
      if (n < T_) {
        const int ct0 = slot*128;           // 128 cols, K=256(+E)
        const int cell = slot >> 3;
        GateEpiM<8> epi{ cell ? lc1o : GC1C,
                         cell ? lh1n : GH1P,
                         cell ? lc1n : GC1P,
                         BG1P, rows0, ct0 };
        mm_lds<8,1,true,8>(cell ? lh1o : GH1C, nullptr, nullptr, nullptr,
                           WE1, 2048, ex, rows0, ct0, epi);
      }
    } else if (n >= 1) {
      const int ct0 = s2*64;                // 64 cols, K=512
      GateEpiM<4> epi{ GC2C, GH2P, GC2P, BG2P, rows0, ct0 };
      mm_lds<16,2,false,4>(GH1C, GH2C, nullptr, nullptr,
                           nullptr, 0, nullptr, rows0, ct0, epi);
    }
    __syncthreads();
    { // issue P_B weights
      if (slot < 16) dma64(WP1PK + (size_t)s2*32768);
      else           dma64(WP2PK + (size_t)s2*32768);
    }
    gbar_x(arr, slot, ++ep);

    // ===== P_B: full-K MLP1 (slots 0-15) || full-K MLP2 (slots 16-31) =====
    if (slot < 16) {
      if (n < T_) {
        const int ct0 = s2*32;              // 32 cols, K=1024(+E)
        MlpEpiH epi{ M1H, in.p1_b1, rows0, ct0 };
        mm_lds<32,4,true,2>(GH1P, GC1P, lh1n, lc1n,
                            WEP1, 512, ex, rows0, ct0, epi);
      }
    } else if (n >= 1) {
      const int ct0 = s2*32;
      MlpEpiH epi{ M2H, in.p2_b1, rows0, ct0 };
      mm_lds<32,4,true,2>(GH2P, GC2P, lh2o, lc2o,
                          WEP2, 512, exm, rows0, ct0, epi);
    }
    __syncthreads();
    if (n < T_) { // issue P_C / next P_A weights
      if (slot < 16) dma64(WL2PK + (size_t)slot*32768);      // l2 this cycle
      else           dma64(WG2PK + (size_t)s2*32768);        // g2 next cycle
    }
    gbar_x(arr, slot, ++ep);

    // ===== P_C =====
    if (slot < 16) {
      if (n < T_) {
        const int ct0 = slot*64;            // 64 cols, K=512
        GateEpiM<4> epi{ lc2o, lh2n, lc2n, BL2P, rows0, ct0 };
        mm_lds<16,2,false,4>(lh1n, lh2o, nullptr, nullptr,
                             nullptr, 0, nullptr, rows0, ct0, epi);
      }
    } else if (slot < 24) {
      if (n < T_) {
        const int rb = rows0 + (slot-16)*16;
        stage_F2(rb, M1H, WB1PK, in.p1_b2, in.p1_W3, in.p1_b3,
                 lh1n, lc1n, GH1P, GC1P, GH1C, GC1C);
        if (n + 1 < T_ && threadIdx.x < 128) {
          const int r = rb + (threadIdx.x >> 3), j = threadIdx.x & 7;
          EXB[(sel^1)*(B_*8) + r*8 + j] =
              in.emb[(size_t)in.seq[(size_t)r*T_ + n + 1]*8 + j];
        }
      }
    } else {
      if (n >= 1) {
        const int rb = rows0 + (slot-24)*16;
        stage_F2(rb, M2H, WB2PK, in.p2_b2, in.p2_W3, in.p2_b3,
                 lh2o, lc2o, GH2P, GC2P, GH2C, GC2C);
        __syncthreads();
        stage_OUTS(GH2C, WOUT, BOUT, OSTG, rb, n-1);
        if (((n-1) & 15) == 15) {
          __syncthreads();
          flush_out(OSTG, out, rb, n-16);
        }
      }
    }
    __syncthreads();
    if (n < T_ - 1) {  // issue next cycle's P_A weights (gates1) for slots<16
      if (slot < 16) dma64(WG1PK + (size_t)slot*32768);
    }
    gbar_x(arr, slot, ++ep);
  }
}

// ---------------- host ----------------
extern "C" void kernel_launch(void* const* d_in, const int* in_sizes, int n_in,
                              void* d_out, int out_size, void* d_ws, size_t ws_size,
                              hipStream_t stream)
{
  if (ws_size < WS_FLOATS * sizeof(float)) return;

  InP in;
  in.seq    = (const int*)  d_in[0];
  in.emb    = (const float*)d_in[1];
  in.g1_Wih = (const float*)d_in[2];  in.g1_Whh = (const float*)d_in[3];
  in.g1_bih = (const float*)d_in[4];  in.g1_bhh = (const float*)d_in[5];
  in.g2_Wih = (const float*)d_in[6];  in.g2_Whh = (const float*)d_in[7];
  in.g2_bih = (const float*)d_in[8];  in.g2_bhh = (const float*)d_in[9];
  in.l1_Wih = (const float*)d_in[10]; in.l1_Whh = (const float*)d_in[11];
  in.l1_bih = (const float*)d_in[12]; in.l1_bhh = (const float*)d_in[13];
  in.l2_Wih = (const float*)d_in[14]; in.l2_Whh = (const float*)d_in[15];
  in.l2_bih = (const float*)d_in[16]; in.l2_bhh = (const float*)d_in[17];
  in.p1_W1  = (const float*)d_in[18]; in.p1_b1  = (const float*)d_in[19];
  in.p1_W2  = (const float*)d_in[20]; in.p1_b2  = (const float*)d_in[21];
  in.p1_W3  = (const float*)d_in[22]; in.p1_b3  = (const float*)d_in[23];
  in.p2_W1  = (const float*)d_in[24]; in.p2_b1  = (const float*)d_in[25];
  in.p2_W2  = (const float*)d_in[26]; in.p2_b2  = (const float*)d_in[27];
  in.p2_W3  = (const float*)d_in[28]; in.p2_b3  = (const float*)d_in[29];
  in.gfc_W  = (const float*)d_in[30]; in.gfc_b  = (const float*)d_in[31];
  in.lfc_W  = (const float*)d_in[32]; in.lfc_b  = (const float*)d_in[33];

  float* ws  = (float*)d_ws;
  float* out = (float*)d_out;

  k_setup<<<512, 256, 0, stream>>>(in, ws);
  k_main <<<NBLK, NTHR, 65536, stream>>>(in, ws, out);   // 64KB dyn LDS (B tiles)
}

// Round 14
// 56917.291 us; speedup vs baseline: 1.4416x; 1.0122x over previous
//
#include <hip/hip_runtime.h>

#define B_ 1024
#define T_ 256
#define V_ 90
#define H_ 256
#define NTHR 512
#define NBLK 256
#define S_ ((size_t)B_*H_)
#define HS_ (S_/2)

typedef unsigned short u16;
typedef __attribute__((ext_vector_type(8))) _Float16 f16x8;
typedef __attribute__((ext_vector_type(4))) _Float16 f16x4;
typedef __attribute__((ext_vector_type(4))) float f32x4;

// ---------------- ws layout (float offsets) ----------------
// fp16 h-state (u16[B][256], ping-pong where needed)
constexpr size_t OFF_GH1C  = 0;                    // HS_
constexpr size_t OFF_GH1P  = OFF_GH1C + HS_;
constexpr size_t OFF_LH1   = OFF_GH1P + HS_;       // 2 bufs
constexpr size_t OFF_GH2C  = OFF_LH1 + 2*HS_;
constexpr size_t OFF_GH2P  = OFF_GH2C + HS_;
constexpr size_t OFF_LH2   = OFF_GH2P + HS_;       // 2 bufs
// fp16 c GEMM copies
constexpr size_t OFF_GC1PH = OFF_LH2 + 2*HS_;
constexpr size_t OFF_LC1H  = OFF_GC1PH + HS_;      // 2 bufs
constexpr size_t OFF_GC2PH = OFF_LC1H + 2*HS_;
constexpr size_t OFF_LC2H  = OFF_GC2PH + HS_;      // 2 bufs
// fp32 c masters
constexpr size_t OFF_GC1C  = OFF_LC2H + 2*HS_;
constexpr size_t OFF_GC1P  = OFF_GC1C + S_;
constexpr size_t OFF_LC1   = OFF_GC1P + S_;        // 2 bufs
constexpr size_t OFF_GC2C  = OFF_LC1 + 2*S_;
constexpr size_t OFF_GC2P  = OFF_GC2C + S_;
constexpr size_t OFF_LC2   = OFF_GC2P + S_;        // 2 bufs
constexpr size_t OFF_M1H   = OFF_LC2 + 2*S_;       // fp16 [B][512]
constexpr size_t OFF_M2H   = OFF_M1H + (size_t)B_*512/2;
constexpr size_t OFF_OSTG  = OFF_M2H + (size_t)B_*512/2;  // [B][16][90] fp32
constexpr size_t OFF_EX    = OFF_OSTG + (size_t)B_*16*90;
// fp16 packed weights, per-block-contiguous 64KB slices (layouts = R12)
constexpr size_t OFF_WG1PK = OFF_EX + 2*B_*8;
constexpr size_t OFF_WE1   = OFF_WG1PK + 256*2048/2;
constexpr size_t OFF_BG1   = OFF_WE1 + 8*2048;
constexpr size_t OFF_WL2PK = OFF_BG1 + 2048;
constexpr size_t OFF_BL2   = OFF_WL2PK + 512*1024/2;
constexpr size_t OFF_WG2PK = OFF_BL2 + 1024;
constexpr size_t OFF_BG2   = OFF_WG2PK + 512*1024/2;
constexpr size_t OFF_WP1PK = OFF_BG2 + 1024;
constexpr size_t OFF_WEP1  = OFF_WP1PK + 1024*512/2;
constexpr size_t OFF_WP2PK = OFF_WEP1 + 8*512;
constexpr size_t OFF_WEP2  = OFF_WP2PK + 1024*512/2;
constexpr size_t OFF_WB1   = OFF_WEP2 + 8*512;     // fp16 [512][256]
constexpr size_t OFF_WB2   = OFF_WB1 + 512*256/2;
constexpr size_t OFF_WOUT  = OFF_WB2 + 512*256/2;  // fp32 [256][96]
constexpr size_t OFF_BOUT  = OFF_WOUT + 256*96;
constexpr size_t OFF_BAR   = OFF_BOUT + 128;
constexpr size_t WS_FLOATS = OFF_BAR + 8192;

struct InP {
  const int*   seq;
  const float* emb;
  const float *g1_Wih,*g1_Whh,*g1_bih,*g1_bhh;
  const float *g2_Wih,*g2_Whh,*g2_bih,*g2_bhh;
  const float *l1_Wih,*l1_Whh,*l1_bih,*l1_bhh;
  const float *l2_Wih,*l2_Whh,*l2_bih,*l2_bhh;
  const float *p1_W1,*p1_b1,*p1_W2,*p1_b2,*p1_W3,*p1_b3;
  const float *p2_W1,*p2_b1,*p2_W2,*p2_b2,*p2_W3,*p2_b3;
  const float *gfc_W,*gfc_b,*lfc_W,*lfc_b;
};

__device__ __forceinline__ float sig_(float x)  { return 1.f/(1.f+__expf(-x)); }
__device__ __forceinline__ float tanh_(float x) { return 1.f - 2.f/(__expf(2.f*x)+1.f); }
__device__ __forceinline__ u16 f2h(float v) {
  _Float16 h = (_Float16)v; return __builtin_bit_cast(unsigned short, h);
}

// ---- AGENT-scope (sc1) flag ops (R7-proven) ----
__device__ __forceinline__ unsigned ld_flag(const unsigned* p) {
  unsigned v;
  asm volatile("global_load_dword %0, %1, off sc1\n\ts_waitcnt vmcnt(0)"
               : "=v"(v) : "v"(p) : "memory");
  return v;
}
__device__ __forceinline__ void st_flag(unsigned* p, unsigned v) {
  asm volatile("global_store_dword %0, %1, off sc1\n\ts_waitcnt vmcnt(0)"
               :: "v"(p), "v"(v) : "memory");
}

// -------- per-XCD barrier: all-poll epoch flags (R9-proven) --------
__device__ __forceinline__ void gbar_x(unsigned* arr, int slot, unsigned ep)
{
  __syncthreads();                       // drains vmcnt(0): stores + DMA done
  if (threadIdx.x == 0) st_flag(&arr[slot*16], ep);
  if (threadIdx.x < 32) {
    int cap = 0;
    for (;;) {
      unsigned v = ld_flag(&arr[threadIdx.x*16]);
      if (v >= ep) break;
      __builtin_amdgcn_s_sleep(1);
      if (++cap > 200000) break;
    }
  }
  __syncthreads();
  asm volatile("buffer_inv sc0" ::: "memory");   // vL1 invalidate only
}

// -------- async weight DMA: 64KB contiguous global -> LDS buffer --------
__device__ __forceinline__ void gl_lds16(const void* g, void* l) {
  __builtin_amdgcn_global_load_lds(
      (const __attribute__((address_space(1))) unsigned int*)g,
      (__attribute__((address_space(3))) unsigned int*)l, 16, 0, 2);  // NT
}
__device__ __forceinline__ void dma64(const u16* src, u16* dstbase) {
  const int wv = threadIdx.x >> 6, lane = threadIdx.x & 63;
  const char* g = (const char*)src + lane*16;
  char* l = (char*)dstbase;
#pragma unroll
  for (int j = 0; j < 8; ++j) {
    const int ofs = (wv*8 + j) * 1024;     // 8 waves x 8KB = 64KB
    gl_lds16(g + ofs, l + ofs);
  }
}

// ====== fp16 MFMA tile GEMM: 128 rows x (TPW*16) cols, 8 row-wave-strips ======
// B in LDS buffer bufp (DMA'd previous phase, drained at gbar). A: fp16 state,
// one 16B load per chunk, depth-8 ring, no syncs in loop.
// A frag: lane&15 = row, k = (lane>>4)*8 + e.  C/D: col=l&15, row=(l>>4)*4+reg.
template<int NCH, int NSEG, bool HASE, int TPW, class FE>
__device__ __forceinline__ void mm_lds(
    const u16* bufp,
    const u16* s0, const u16* s1_, const u16* s2_, const u16* s3_,
    const float* WeP, int ldwe, const float* ex,
    int rows0, int ct0, FE fe)
{
  const int tid = threadIdx.x, lane = tid & 63, wr = tid >> 6;
  const int row = rows0 + wr*16 + (lane & 15);
  const int kq  = (lane >> 4) << 3;

  f32x4 acc[TPW];
#pragma unroll
  for (int t = 0; t < TPW; ++t) acc[t] = (f32x4){0,0,0,0};

  constexpr int DEP = (NCH < 8) ? NCH : 8;
  f16x8 areg[DEP];
  auto ldA = [&](int c) -> f16x8 {
    const int k0 = c * 32;
    const u16* S;
    if (NSEG == 1) S = s0;
    else if (NSEG == 2) S = (k0 < 256) ? s0 : s1_;
    else S = (k0 < 256) ? s0 : (k0 < 512) ? s1_ : (k0 < 768) ? s2_ : s3_;
    return *(const f16x8*)&S[(size_t)row*H_ + (k0 & 255) + kq];
  };

#pragma unroll
  for (int c = 0; c < DEP; ++c) areg[c] = ldA(c);
#pragma unroll
  for (int c = 0; c < NCH; ++c) {
    f16x8 a = areg[c % DEP];
#pragma unroll
    for (int t = 0; t < TPW; ++t) {
      f16x8 b = *(const f16x8*)(bufp + (size_t)(c*TPW + t)*512 + lane*8);
      acc[t] = __builtin_amdgcn_mfma_f32_16x16x32_f16(a, b, acc[t], 0, 0, 0);
    }
    if (c + DEP < NCH) areg[c % DEP] = ldA(c + DEP);
  }

  if (HASE) {   // E-correction (K=8 embedding part)
#pragma unroll
    for (int t = 0; t < TPW; ++t) {
      const int colL = ct0 + t*16 + (lane & 15);
      float w[8];
#pragma unroll
      for (int j = 0; j < 8; ++j) w[j] = WeP[j*ldwe + colL];
#pragma unroll
      for (int m = 0; m < 4; ++m) {
        const int rr = rows0 + wr*16 + ((lane >> 4) << 2) + m;
        float s = 0.f;
#pragma unroll
        for (int j = 0; j < 8; ++j) s = __builtin_fmaf(ex[rr*8 + j], w[j], s);
        acc[t][m] += s;
      }
    }
  }
  fe(wr, lane, acc);
}

// ---------------- epilogues ----------------
template<int TPW>
struct GateEpiM {
  const float* cin; u16* ho; float* co; u16* coh; const float* bias_pk;
  int rows0; int ct0;
  __device__ void operator()(int wr, int lane, f32x4 (&acc)[TPW]) const {
    const int rbase = rows0 + wr*16 + ((lane >> 4) << 2);
#pragma unroll
    for (int gi = 0; gi < TPW/4; ++gi) {
      const int cb = ct0 + gi*64;
      const int h = (((cb & 1023) >> 6) << 4) + (lane & 15);
      float b[4];
#pragma unroll
      for (int t = 0; t < 4; ++t) b[t] = bias_pk[cb + t*16 + (lane & 15)];
#pragma unroll
      for (int m = 0; m < 4; ++m) {
        const size_t ix = (size_t)(rbase + m)*H_ + h;
        float gI = sig_(acc[gi*4+0][m] + b[0]);
        float gF = sig_(acc[gi*4+1][m] + b[1]);
        float gG = tanh_(acc[gi*4+2][m] + b[2]);
        float gO = sig_(acc[gi*4+3][m] + b[3]);
        float cn = gF*cin[ix] + gI*gG;
        ho[ix] = f2h(gO*tanh_(cn));
        co[ix] = cn;
        coh[ix] = f2h(cn);
      }
    }
  }
};

struct MlpEpiH {
  u16* dst; const float* b1; int rows0; int ct0;
  __device__ void operator()(int wr, int lane, f32x4 (&acc)[2]) const {
    const int rbase = rows0 + wr*16 + ((lane >> 4) << 2);
#pragma unroll
    for (int t = 0; t < 2; ++t) {
      const int c = ct0 + t*16 + (lane & 15);
      const float bb = b1[c];
#pragma unroll
      for (int m = 0; m < 4; ++m)
        dst[(size_t)(rbase + m)*512 + c] = f2h(fmaxf(acc[t][m] + bb, 0.f));
    }
  }
};

// ---- fused p-MLP2 + head + softmax + mix (fp16 M/WB/h, fp32 c) ----
__device__ __forceinline__ void stage_F2(
    int rowbase,
    const u16* M, const u16* WBpk, const float* b2,
    const float* W3, const float* b3,
    const u16* lh, const float* lc,
    const u16* ghp, const float* gcp,
    u16* ghc, float* gcc)
{
  const int w = threadIdx.x >> 6, lane = threadIdx.x & 63;
  const int r0 = rowbase + w*2;
  const u16* a0 = M + (size_t)r0*512;
  const u16* a1 = a0 + 512;
  float m0[4] = {0.f,0.f,0.f,0.f}, m1[4] = {0.f,0.f,0.f,0.f};
  for (int k0 = 0; k0 < 512; k0 += 4) {
    f16x4 x0 = *(const f16x4*)&a0[k0];
    f16x4 x1 = *(const f16x4*)&a1[k0];
#pragma unroll
    for (int j = 0; j < 4; ++j) {
      f16x4 wv = *(const f16x4*)&WBpk[(size_t)(k0+j)*256 + lane*4];
      float w0 = (float)wv[0], w1 = (float)wv[1], w2 = (float)wv[2], w3v = (float)wv[3];
      float xv0 = (float)x0[j], xv1 = (float)x1[j];
      m0[0] = __builtin_fmaf(xv0, w0, m0[0]);
      m0[1] = __builtin_fmaf(xv0, w1, m0[1]);
      m0[2] = __builtin_fmaf(xv0, w2, m0[2]);
      m0[3] = __builtin_fmaf(xv0, w3v, m0[3]);
      m1[0] = __builtin_fmaf(xv1, w0, m1[0]);
      m1[1] = __builtin_fmaf(xv1, w1, m1[1]);
      m1[2] = __builtin_fmaf(xv1, w2, m1[2]);
      m1[3] = __builtin_fmaf(xv1, w3v, m1[3]);
    }
  }
  float4 b = *(const float4*)&b2[lane*4];
  float bb2[4] = {b.x,b.y,b.z,b.w};
#pragma unroll
  for (int j = 0; j < 4; ++j) {
    m0[j] = fmaxf(m0[j]+bb2[j], 0.f);
    m1[j] = fmaxf(m1[j]+bb2[j], 0.f);
  }
  float4 w30 = *(const float4*)&W3[lane*4];
  float4 w31 = *(const float4*)&W3[256 + lane*4];
  float w0v[4] = {w30.x,w30.y,w30.z,w30.w};
  float w1v[4] = {w31.x,w31.y,w31.z,w31.w};
  float d00=0.f, d01=0.f, d10=0.f, d11=0.f;
#pragma unroll
  for (int j = 0; j < 4; ++j) {
    d00 = __builtin_fmaf(m0[j], w0v[j], d00);
    d01 = __builtin_fmaf(m0[j], w1v[j], d01);
    d10 = __builtin_fmaf(m1[j], w0v[j], d10);
    d11 = __builtin_fmaf(m1[j], w1v[j], d11);
  }
#pragma unroll
  for (int off = 32; off; off >>= 1) {
    d00 += __shfl_xor(d00, off, 64); d01 += __shfl_xor(d01, off, 64);
    d10 += __shfl_xor(d10, off, 64); d11 += __shfl_xor(d11, off, 64);
  }
  d00 += b3[0]; d01 += b3[1]; d10 += b3[0]; d11 += b3[1];
  float mxa = fmaxf(d00, d01), mxb = fmaxf(d10, d11);
  float e00 = __expf(d00-mxa), e01 = __expf(d01-mxa);
  float e10 = __expf(d10-mxb), e11 = __expf(d11-mxb);
  float ia = 1.f/(e00+e01), ib = 1.f/(e10+e11);
  float p0a = e00*ia, p1a = e01*ia;
  float p0b = e10*ib, p1b = e11*ib;
#pragma unroll
  for (int rr = 0; rr < 2; ++rr) {
    const float p0 = rr ? p0b : p0a, p1 = rr ? p1b : p1a;
    const size_t ix = (size_t)(r0+rr)*H_ + lane*4;
    f16x4 lv = *(const f16x4*)&lh[ix];
    f16x4 gv = *(const f16x4*)&ghp[ix];
    f16x4 oh;
#pragma unroll
    for (int j = 0; j < 4; ++j)
      oh[j] = (_Float16)(p0*(float)lv[j] + p1*(float)gv[j]);
    *(f16x4*)&ghc[ix] = oh;
    float4 lcv = *(const float4*)&lc[ix];
    float4 gcv = *(const float4*)&gcp[ix];
    float4 oc;
    oc.x = p0*lcv.x + p1*gcv.x; oc.y = p0*lcv.y + p1*gcv.y;
    oc.z = p0*lcv.z + p1*gcv.z; oc.w = p0*lcv.w + p1*gcv.w;
    *(float4*)&gcc[ix] = oc;
  }
}

// -------- output projection -> staging buffer [r][t&15][90] --------
__device__ __forceinline__ void stage_OUTS(
    const u16* gh2c, const float* WOUT, const float* BOUT,
    float* ostg, int rbase, int tt)
{
  const int w = threadIdx.x >> 6, lane = threadIdx.x & 63;
  const bool two = lane < (V_ - 64);
#pragma unroll
  for (int rr = 0; rr < 2; ++rr) {
    const int r = rbase + w*2 + rr;
    const u16* arow = gh2c + (size_t)r * H_;
    float acc0 = 0.f, acc1 = 0.f;
    for (int k0 = 0; k0 < 256; k0 += 8) {
      f16x8 a8 = *(const f16x8*)&arow[k0];
#pragma unroll
      for (int j = 0; j < 8; ++j) {
        const float av = (float)a8[j];
        const float* wr_ = &WOUT[(size_t)(k0+j)*96];
        acc0 = __builtin_fmaf(av, wr_[lane], acc0);
        if (two) acc1 = __builtin_fmaf(av, wr_[64+lane], acc1);
      }
    }
    float* dst = &ostg[((size_t)r*16 + (tt & 15))*90];
    dst[lane] = acc0 + BOUT[lane];
    if (two) dst[64+lane] = acc1 + BOUT[64+lane];
  }
}

// -------- flush 16 t-columns: full-line 64B writes to out --------
__device__ __forceinline__ void flush_out(
    const float* ostg, float* out, int rbase, int tb0)
{
  for (int i = threadIdx.x; i < 16*90; i += NTHR) {
    const int rr = i / 90, v = i - rr*90;
    const int r = rbase + rr;
    const float* src = &ostg[((size_t)r*16)*90 + v];
    float tmp[16];
#pragma unroll
    for (int tb = 0; tb < 16; ++tb) tmp[tb] = src[tb*90];
    float* dst = &out[((size_t)r*V_ + v)*T_ + tb0];
#pragma unroll
    for (int q = 0; q < 4; ++q)
      ((float4*)dst)[q] = make_float4(tmp[q*4], tmp[q*4+1], tmp[q*4+2], tmp[q*4+3]);
  }
}

// ---------------- setup (weight layouts identical to R12) ----------------
__global__ void k_setup(InP in, float* __restrict__ ws)
{
  const size_t nthr = (size_t)gridDim.x * blockDim.x;
  const size_t t0 = (size_t)blockIdx.x * blockDim.x + threadIdx.x;

  for (size_t i = t0; i < OFF_M1H; i += nthr) ws[i] = 0.f;  // all states zero
  for (size_t i = t0; i < 8192; i += nthr) ((unsigned*)(ws + OFF_BAR))[i] = 0u;

  for (size_t i = t0; i < (size_t)B_*8; i += nthr) {
    int r = (int)(i >> 3), j = (int)(i & 7);
    ws[OFF_EX + i] = in.emb[(size_t)in.seq[(size_t)r*T_]*8 + j];
  }

  {
    u16* dst = (u16*)(ws + OFF_WG1PK);
    for (size_t i = t0; i < (size_t)16*8*8*512; i += nthr) {
      int e = (int)(i & 7), lane = (int)((i >> 3) & 63);
      int tile = (int)((i >> 9) & 7), ck = (int)((i >> 12) & 7), blk = (int)(i >> 15);
      int col = blk*128 + tile*16 + (lane & 15);
      int k = ck*32 + ((lane >> 4) << 3) + e;
      int cell = col >> 10, q = col & 1023;
      int h = ((q >> 6) << 4) + (q & 15), g = (q >> 4) & 3, R = g*256 + h;
      dst[i] = f2h((cell ? in.l1_Whh : in.g1_Whh)[(size_t)R*256 + k]);
    }
  }
  for (size_t i = t0; i < (size_t)8*2048; i += nthr) {
    int j = (int)(i >> 11), p = (int)(i & 2047);
    int cell = p >> 10, q = p & 1023;
    int h = ((q >> 6) << 4) + (q & 15), g = (q >> 4) & 3, R = g*256 + h;
    ws[OFF_WE1 + (size_t)j*2048 + p] = (cell ? in.l1_Wih : in.g1_Wih)[(size_t)R*8 + j];
  }
  for (size_t i = t0; i < 2048; i += nthr) {
    int p = (int)i, cell = p >> 10, q = p & 1023;
    int h = ((q >> 6) << 4) + (q & 15), g = (q >> 4) & 3, R = g*256 + h;
    ws[OFF_BG1 + i] = cell ? (in.l1_bih[R] + in.l1_bhh[R]) : (in.g1_bih[R] + in.g1_bhh[R]);
  }

  for (int which = 0; which < 2; ++which) {
    u16* dst = (u16*)(ws + (which ? OFF_WG2PK : OFF_WL2PK));
    const float* Wih = which ? in.g2_Wih : in.l2_Wih;
    const float* Whh = which ? in.g2_Whh : in.l2_Whh;
    for (size_t i = t0; i < (size_t)16*16*4*512; i += nthr) {
      int e = (int)(i & 7), lane = (int)((i >> 3) & 63);
      int tile = (int)((i >> 9) & 3), ck = (int)((i >> 11) & 15), blk = (int)(i >> 15);
      int col = blk*64 + tile*16 + (lane & 15);
      int k = ck*32 + ((lane >> 4) << 3) + e;
      int h = ((col >> 6) << 4) + (col & 15), g = (col >> 4) & 3, R = g*256 + h;
      float w = (k < 256) ? Wih[(size_t)R*256 + k] : Whh[(size_t)R*256 + (k-256)];
      dst[i] = f2h(w);
    }
  }
  for (size_t i = t0; i < 2*1024; i += nthr) {
    int which = (int)(i >> 10), p = (int)(i & 1023);
    int h = ((p >> 6) << 4) + (p & 15), g = (p >> 4) & 3, R = g*256 + h;
    float v = which ? (in.g2_bih[R] + in.g2_bhh[R]) : (in.l2_bih[R] + in.l2_bhh[R]);
    ws[(which ? OFF_BG2 : OFF_BL2) + p] = v;
  }

  for (int which = 0; which < 2; ++which) {
    u16* dst = (u16*)(ws + (which ? OFF_WP2PK : OFF_WP1PK));
    const float* W = which ? in.p2_W1 : in.p1_W1;
    for (size_t i = t0; i < (size_t)16*32*2*512; i += nthr) {
      int e = (int)(i & 7), lane = (int)((i >> 3) & 63);
      int tile = (int)((i >> 9) & 1), ck = (int)((i >> 10) & 31), blk = (int)(i >> 15);
      int col = blk*32 + tile*16 + (lane & 15);
      int k = ck*32 + ((lane >> 4) << 3) + e;
      dst[i] = f2h(W[(size_t)col*1032 + 8 + k]);
    }
  }
  for (size_t i = t0; i < (size_t)2*8*512; i += nthr) {
    int which = (int)(i / (8*512));
    int idx = (int)(i - (size_t)which*8*512);
    int j = idx >> 9, p = idx & 511;
    const float* W = which ? in.p2_W1 : in.p1_W1;
    ws[(which ? OFF_WEP2 : OFF_WEP1) + (size_t)j*512 + p] = W[(size_t)p*1032 + j];
  }

  for (size_t i = t0; i < (size_t)2*512*256; i += nthr) {
    int which = (int)(i / (512*256));
    int idx = (int)(i - (size_t)which*512*256);
    int k = idx >> 8, n = idx & 255;
    const float* W = which ? in.p2_W2 : in.p1_W2;
    ((u16*)(ws + (which ? OFF_WB2 : OFF_WB1)))[idx] = f2h(W[(size_t)n*512 + k]);
  }
  for (size_t i = t0; i < (size_t)256*96; i += nthr) {
    int k = (int)(i / 96), c = (int)(i - (size_t)k*96);
    float v = 0.f;
    if (c < V_) v = 0.5f*(in.gfc_W[(size_t)c*256 + k] + in.lfc_W[(size_t)c*256 + k]);
    ws[OFF_WOUT + i] = v;
  }
  for (size_t i = t0; i < 96; i += nthr)
    ws[OFF_BOUT + i] = (i < V_) ? 0.5f*(in.gfc_b[i] + in.lfc_b[i]) : 0.f;
}

// ------- main: 3-phase pipeline, dbuf DMA-at-phase-start, fp16 state -------
__global__ __launch_bounds__(NTHR) void k_main(InP in, float* ws, float* __restrict__ out)
{
  __shared__ __attribute__((aligned(16))) u16 sB0[32768];   // 64KB buffer 0
  extern __shared__ u16 dynB[];                             // 64KB buffer 1
  __shared__ unsigned s_slot;

  u16*  GH1C = (u16*)(ws + OFF_GH1C);
  u16*  GH1P = (u16*)(ws + OFF_GH1P);
  u16*  LH1  = (u16*)(ws + OFF_LH1);
  u16*  GH2C = (u16*)(ws + OFF_GH2C);
  u16*  GH2P = (u16*)(ws + OFF_GH2P);
  u16*  LH2  = (u16*)(ws + OFF_LH2);
  u16*  GC1PH= (u16*)(ws + OFF_GC1PH);
  u16*  LC1H = (u16*)(ws + OFF_LC1H);
  u16*  GC2PH= (u16*)(ws + OFF_GC2PH);
  u16*  LC2H = (u16*)(ws + OFF_LC2H);
  float* GC1C = ws + OFF_GC1C;  float* GC1P = ws + OFF_GC1P;
  float* LC1  = ws + OFF_LC1;
  float* GC2C = ws + OFF_GC2C;  float* GC2P = ws + OFF_GC2P;
  float* LC2  = ws + OFF_LC2;
  u16*   M1H  = (u16*)(ws + OFF_M1H);
  u16*   M2H  = (u16*)(ws + OFF_M2H);
  float* OSTG = ws + OFF_OSTG;
  float* EXB  = ws + OFF_EX;
  const u16* WG1PK = (const u16*)(ws + OFF_WG1PK);
  const u16* WL2PK = (const u16*)(ws + OFF_WL2PK);
  const u16* WG2PK = (const u16*)(ws + OFF_WG2PK);
  const u16* WP1PK = (const u16*)(ws + OFF_WP1PK);
  const u16* WP2PK = (const u16*)(ws + OFF_WP2PK);
  const u16* WB1PK = (const u16*)(ws + OFF_WB1);
  const u16* WB2PK = (const u16*)(ws + OFF_WB2);
  const float* WE1  = ws + OFF_WE1;  const float* BG1P = ws + OFF_BG1;
  const float* BL2P = ws + OFF_BL2;  const float* BG2P = ws + OFF_BG2;
  const float* WEP1 = ws + OFF_WEP1; const float* WEP2 = ws + OFF_WEP2;
  const float* WOUT = ws + OFF_WOUT; const float* BOUT = ws + OFF_BOUT;

  unsigned xcc;
  asm volatile("s_getreg_b32 %0, hwreg(HW_REG_XCC_ID)" : "=s"(xcc));
  xcc &= 7u;
  unsigned* barx = ((unsigned*)(ws + OFF_BAR)) + xcc*1024;
  unsigned* arr  = barx;
  unsigned* reg  = barx + 544;
  if (threadIdx.x == 0)
    s_slot = __hip_atomic_fetch_add(reg, 1u, __ATOMIC_RELAXED, __HIP_MEMORY_SCOPE_AGENT);
  __syncthreads();
  const int slot  = (int)(s_slot & 31u);
  const int rows0 = (int)xcc * 128;
  const int s2 = slot & 15;
  unsigned ep = 0;
  int wb = 0;   // parity: 0 -> compute from sB0, fetch into dynB

  // prologue: fetch first P_A weights into sB0, drain
  if (slot < 16) dma64(WG1PK + (size_t)slot*32768, sB0);
  else           dma64(WG2PK + (size_t)s2*32768, sB0);
  asm volatile("s_waitcnt vmcnt(0)" ::: "memory");
  __syncthreads();

  for (int n = 0; n <= T_; ++n) {
    const int sel = n & 1;
    const float* ex  = EXB + sel*(B_*8);
    const float* exm = EXB + (sel^1)*(B_*8);
    u16* lh1o = LH1 + sel*(B_*H_);   u16* lh1n = LH1 + (sel^1)*(B_*H_);
    float* lc1o = LC1 + sel*S_;      float* lc1n = LC1 + (sel^1)*S_;
    u16* lc1nh = LC1H + (sel^1)*(B_*H_);
    u16* lh2o = LH2 + sel*(B_*H_);   u16* lh2n = LH2 + (sel^1)*(B_*H_);
    float* lc2o = LC2 + sel*S_;      float* lc2n = LC2 + (sel^1)*S_;
    u16* lc2oh = LC2H + sel*(B_*H_); u16* lc2nh = LC2H + (sel^1)*(B_*H_);

    u16* bC; u16* bF;   // compute buffer / fetch buffer (runtime select, no array)

    // ===== P_A: issue P_B weights, compute gates1 || g2(n-1) =====
    bC = wb ? dynB : sB0; bF = wb ? sB0 : dynB;
    if (slot < 16) dma64(WP1PK + (size_t)s2*32768, bF);
    else           dma64(WP2PK + (size_t)s2*32768, bF);
    if (slot < 16) {
      if (n < T_) {
        const int ct0 = slot*128;
        const int cell = slot >> 3;
        GateEpiM<8> epi{ cell ? lc1o : GC1C,
                         cell ? lh1n : GH1P,
                         cell ? lc1n : GC1P,
                         cell ? lc1nh : GC1PH,
                         BG1P, rows0, ct0 };
        mm_lds<8,1,true,8>(bC, cell ? lh1o : GH1C, nullptr, nullptr, nullptr,
                           WE1, 2048, ex, rows0, ct0, epi);
      }
    } else if (n >= 1) {
      const int ct0 = s2*64;
      GateEpiM<4> epi{ GC2C, GH2P, GC2P, GC2PH, BG2P, rows0, ct0 };
      mm_lds<16,2,false,4>(bC, GH1C, GH2C, nullptr, nullptr,
                           nullptr, 0, nullptr, rows0, ct0, epi);
    }
    gbar_x(arr, slot, ++ep);
    wb ^= 1;

    // ===== P_B: issue P_C / next P_A weights, compute MLP1 || MLP2(n-1) =====
    bC = wb ? dynB : sB0; bF = wb ? sB0 : dynB;
    if (slot < 16) dma64(WL2PK + (size_t)slot*32768, bF);
    else           dma64(WG2PK + (size_t)s2*32768, bF);
    if (slot < 16) {
      if (n < T_) {
        const int ct0 = s2*32;
        MlpEpiH epi{ M1H, in.p1_b1, rows0, ct0 };
        mm_lds<32,4,true,2>(bC, GH1P, GC1PH, lh1n, lc1nh,
                            WEP1, 512, ex, rows0, ct0, epi);
      }
    } else if (n >= 1) {
      const int ct0 = s2*32;
      MlpEpiH epi{ M2H, in.p2_b1, rows0, ct0 };
      mm_lds<32,4,true,2>(bC, GH2P, GC2PH, lh2o, lc2oh,
                          WEP2, 512, exm, rows0, ct0, epi);
    }
    gbar_x(arr, slot, ++ep);
    wb ^= 1;

    // ===== P_C: slots<16 issue next P_A weights + compute l2; others F2 =====
    bC = wb ? dynB : sB0; bF = wb ? sB0 : dynB;
    if (slot < 16) {
      dma64(WG1PK + (size_t)slot*32768, bF);
      if (n < T_) {
        const int ct0 = slot*64;
        GateEpiM<4> epi{ lc2o, lh2n, lc2n, lc2nh, BL2P, rows0, ct0 };
        mm_lds<16,2,false,4>(bC, lh1n, lh2o, nullptr, nullptr,
                             nullptr, 0, nullptr, rows0, ct0, epi);
      }
    } else if (slot < 24) {
      if (n < T_) {
        const int rb = rows0 + (slot-16)*16;
        stage_F2(rb, M1H, WB1PK, in.p1_b2, in.p1_W3, in.p1_b3,
                 lh1n, lc1n, GH1P, GC1P, GH1C, GC1C);
        if (n + 1 < T_ && threadIdx.x < 128) {
          const int r = rb + (threadIdx.x >> 3), j = threadIdx.x & 7;
          EXB[(sel^1)*(B_*8) + r*8 + j] =
              in.emb[(size_t)in.seq[(size_t)r*T_ + n + 1]*8 + j];
        }
      }
    } else {
      if (n >= 1) {
        const int rb = rows0 + (slot-24)*16;
        stage_F2(rb, M2H, WB2PK, in.p2_b2, in.p2_W3, in.p2_b3,
                 lh2o, lc2o, GH2P, GC2P, GH2C, GC2C);
        __syncthreads();
        stage_OUTS(GH2C, WOUT, BOUT, OSTG, rb, n-1);
        if (((n-1) & 15) == 15) {
          __syncthreads();
          flush_out(OSTG, out, rb, n-16);
        }
      }
    }
    gbar_x(arr, slot, ++ep);
    if (slot < 16) wb ^= 1;      // slots>=16: no P_C fetch -> keep parity
  }
}

// ---------------- host ----------------
extern "C" void kernel_launch(void* const* d_in, const int* in_sizes, int n_in,
                              void* d_out, int out_size, void* d_ws, size_t ws_size,
                              hipStream_t stream)
{
  if (ws_size < WS_FLOATS * sizeof(float)) return;

  InP in;
  in.seq    = (const int*)  d_in[0];
  in.emb    = (const float*)d_in[1];
  in.g1_Wih = (const float*)d_in[2];  in.g1_Whh = (const float*)d_in[3];
  in.g1_bih = (const float*)d_in[4];  in.g1_bhh = (const float*)d_in[5];
  in.g2_Wih = (const float*)d_in[6];  in.g2_Whh = (const float*)d_in[7];
  in.g2_bih = (const float*)d_in[8];  in.g2_bhh = (const float*)d_in[9];
  in.l1_Wih = (const float*)d_in[10]; in.l1_Whh = (const float*)d_in[11];
  in.l1_bih = (const float*)d_in[12]; in.l1_bhh = (const float*)d_in[13];
  in.l2_Wih = (const float*)d_in[14]; in.l2_Whh = (const float*)d_in[15];
  in.l2_bih = (const float*)d_in[16]; in.l2_bhh = (const float*)d_in[17];
  in.p1_W1  = (const float*)d_in[18]; in.p1_b1  = (const float*)d_in[19];
  in.p1_W2  = (const float*)d_in[20]; in.p1_b2  = (const float*)d_in[21];
  in.p1_W3  = (const float*)d_in[22]; in.p1_b3  = (const float*)d_in[23];
  in.p2_W1  = (const float*)d_in[24]; in.p2_b1  = (const float*)d_in[25];
  in.p2_W2  = (const float*)d_in[26]; in.p2_b2  = (const float*)d_in[27];
  in.p2_W3  = (const float*)d_in[28]; in.p2_b3  = (const float*)d_in[29];
  in.gfc_W  = (const float*)d_in[30]; in.gfc_b  = (const float*)d_in[31];
  in.lfc_W  = (const float*)d_in[32]; in.lfc_b  = (const float*)d_in[33];

  float* ws  = (float*)d_ws;
  float* out = (float*)d_out;

  k_setup<<<512, 256, 0, stream>>>(in, ws);
  k_main <<<NBLK, NTHR, 65536, stream>>>(in, ws, out);   // 64KB dyn + 64KB static LDS
}

// Round 15
// 55890.497 us; speedup vs baseline: 1.4681x; 1.0184x over previous
//
#include <hip/hip_runtime.h>

#define B_ 1024
#define T_ 256
#define V_ 90
#define H_ 256
#define NTHR 512
#define NBLK 256
#define S_ ((size_t)B_*H_)
#define HS_ (S_/2)

typedef unsigned short u16;
typedef __attribute__((ext_vector_type(8))) _Float16 f16x8;
typedef __attribute__((ext_vector_type(4))) _Float16 f16x4;
typedef __attribute__((ext_vector_type(4))) float f32x4;

// ---------------- ws layout (float offsets) ----------------
constexpr size_t OFF_GH1C  = 0;                    // fp16 h-states
constexpr size_t OFF_GH1P  = OFF_GH1C + HS_;
constexpr size_t OFF_LH1   = OFF_GH1P + HS_;       // 2 bufs
constexpr size_t OFF_GH2C  = OFF_LH1 + 2*HS_;
constexpr size_t OFF_GH2P  = OFF_GH2C + HS_;
constexpr size_t OFF_LH2   = OFF_GH2P + HS_;       // 2 bufs
constexpr size_t OFF_GC1PH = OFF_LH2 + 2*HS_;      // fp16 c copies
constexpr size_t OFF_LC1H  = OFF_GC1PH + HS_;      // 2 bufs
constexpr size_t OFF_GC2PH = OFF_LC1H + 2*HS_;
constexpr size_t OFF_LC2H  = OFF_GC2PH + HS_;      // 2 bufs
constexpr size_t OFF_GC1C  = OFF_LC2H + 2*HS_;     // fp32 c masters
constexpr size_t OFF_GC1P  = OFF_GC1C + S_;
constexpr size_t OFF_LC1   = OFF_GC1P + S_;        // 2 bufs
constexpr size_t OFF_GC2C  = OFF_LC1 + 2*S_;
constexpr size_t OFF_GC2P  = OFF_GC2C + S_;
constexpr size_t OFF_LC2   = OFF_GC2P + S_;        // 2 bufs
constexpr size_t OFF_M1H   = OFF_LC2 + 2*S_;       // fp16 [B][512]
constexpr size_t OFF_M2H   = OFF_M1H + (size_t)B_*512/2;
constexpr size_t OFF_OSTG  = OFF_M2H + (size_t)B_*512/2;  // [B][16][90] fp32
constexpr size_t OFF_EX    = OFF_OSTG + (size_t)B_*16*90;
// fp16 packed weights (canonical copy), per-block-contiguous 64KB slices
constexpr size_t OFF_WG1PK = OFF_EX + 2*B_*8;
constexpr size_t OFF_WE1   = OFF_WG1PK + 256*2048/2;
constexpr size_t OFF_BG1   = OFF_WE1 + 8*2048;
constexpr size_t OFF_WL2PK = OFF_BG1 + 2048;
constexpr size_t OFF_BL2   = OFF_WL2PK + 512*1024/2;
constexpr size_t OFF_WG2PK = OFF_BL2 + 1024;
constexpr size_t OFF_BG2   = OFF_WG2PK + 512*1024/2;
constexpr size_t OFF_WP1PK = OFF_BG2 + 1024;
constexpr size_t OFF_WEP1  = OFF_WP1PK + 1024*512/2;
constexpr size_t OFF_WP2PK = OFF_WEP1 + 8*512;
constexpr size_t OFF_WEP2  = OFF_WP2PK + 1024*512/2;
constexpr size_t OFF_WB1   = OFF_WEP2 + 8*512;     // fp16 [512][256]
constexpr size_t OFF_WB2   = OFF_WB1 + 512*256/2;
constexpr size_t OFF_WOUT  = OFF_WB2 + 512*256/2;  // fp32 [256][96]
constexpr size_t OFF_BOUT  = OFF_WOUT + 256*96;
constexpr size_t OFF_BAR   = OFF_BOUT + 128;
constexpr size_t OFF_WREP  = OFF_BAR + 8192;       // 8 x 5 x 524288 u16 replicas
constexpr size_t WS_FLOATS = OFF_WREP;             // base requirement
constexpr size_t REP_U32   = (size_t)5*262144;     // u32 words per replica
constexpr size_t WS_FULL   = OFF_WREP + 8*REP_U32; // with replicas

struct InP {
  const int*   seq;
  const float* emb;
  const float *g1_Wih,*g1_Whh,*g1_bih,*g1_bhh;
  const float *g2_Wih,*g2_Whh,*g2_bih,*g2_bhh;
  const float *l1_Wih,*l1_Whh,*l1_bih,*l1_bhh;
  const float *l2_Wih,*l2_Whh,*l2_bih,*l2_bhh;
  const float *p1_W1,*p1_b1,*p1_W2,*p1_b2,*p1_W3,*p1_b3;
  const float *p2_W1,*p2_b1,*p2_W2,*p2_b2,*p2_W3,*p2_b3;
  const float *gfc_W,*gfc_b,*lfc_W,*lfc_b;
};

__device__ __forceinline__ float sig_(float x)  { return 1.f/(1.f+__expf(-x)); }
__device__ __forceinline__ float tanh_(float x) { return 1.f - 2.f/(__expf(2.f*x)+1.f); }
__device__ __forceinline__ u16 f2h(float v) {
  _Float16 h = (_Float16)v; return __builtin_bit_cast(unsigned short, h);
}

// ---- AGENT-scope (sc1) flag ops (R7-proven) ----
__device__ __forceinline__ unsigned ld_flag(const unsigned* p) {
  unsigned v;
  asm volatile("global_load_dword %0, %1, off sc1\n\ts_waitcnt vmcnt(0)"
               : "=v"(v) : "v"(p) : "memory");
  return v;
}
__device__ __forceinline__ void st_flag(unsigned* p, unsigned v) {
  asm volatile("global_store_dword %0, %1, off sc1\n\ts_waitcnt vmcnt(0)"
               :: "v"(p), "v"(v) : "memory");
}

// -------- per-XCD barrier: all-poll epoch flags (R9-proven) --------
__device__ __forceinline__ void gbar_x(unsigned* arr, int slot, unsigned ep)
{
  __syncthreads();                       // drains vmcnt(0): stores + DMA done
  if (threadIdx.x == 0) st_flag(&arr[slot*16], ep);
  if (threadIdx.x < 32) {
    int cap = 0;
    for (;;) {
      unsigned v = ld_flag(&arr[threadIdx.x*16]);
      if (v >= ep) break;
      __builtin_amdgcn_s_sleep(1);
      if (++cap > 200000) break;
    }
  }
  __syncthreads();
  asm volatile("buffer_inv sc0" ::: "memory");   // vL1 invalidate only
}

// -------- async weight DMA: 64KB contiguous global -> LDS buffer --------
// aux=0: NORMAL caching (NT removed — weights must be L2/L3 retained; each
// line is re-read 256x over the run. NT forced HBM re-fetch every step.)
__device__ __forceinline__ void gl_lds16(const void* g, void* l) {
  __builtin_amdgcn_global_load_lds(
      (const __attribute__((address_space(1))) unsigned int*)g,
      (__attribute__((address_space(3))) unsigned int*)l, 16, 0, 0);
}
__device__ __forceinline__ void dma64(const u16* src, u16* dstbase) {
  const int wv = threadIdx.x >> 6, lane = threadIdx.x & 63;
  const char* g = (const char*)src + lane*16;
  char* l = (char*)dstbase;
#pragma unroll
  for (int j = 0; j < 8; ++j) {
    const int ofs = (wv*8 + j) * 1024;     // 8 waves x 8KB = 64KB
    gl_lds16(g + ofs, l + ofs);
  }
}

// ====== fp16 MFMA tile GEMM: 128 rows x (TPW*16) cols, 8 row-wave-strips ======
template<int NCH, int NSEG, bool HASE, int TPW, class FE>
__device__ __forceinline__ void mm_lds(
    const u16* bufp,
    const u16* s0, const u16* s1_, const u16* s2_, const u16* s3_,
    const float* WeP, int ldwe, const float* ex,
    int rows0, int ct0, FE fe)
{
  const int tid = threadIdx.x, lane = tid & 63, wr = tid >> 6;
  const int row = rows0 + wr*16 + (lane & 15);
  const int kq  = (lane >> 4) << 3;

  f32x4 acc[TPW];
#pragma unroll
  for (int t = 0; t < TPW; ++t) acc[t] = (f32x4){0,0,0,0};

  constexpr int DEP = (NCH < 8) ? NCH : 8;
  f16x8 areg[DEP];
  auto ldA = [&](int c) -> f16x8 {
    const int k0 = c * 32;
    const u16* S;
    if (NSEG == 1) S = s0;
    else if (NSEG == 2) S = (k0 < 256) ? s0 : s1_;
    else S = (k0 < 256) ? s0 : (k0 < 512) ? s1_ : (k0 < 768) ? s2_ : s3_;
    return *(const f16x8*)&S[(size_t)row*H_ + (k0 & 255) + kq];
  };

#pragma unroll
  for (int c = 0; c < DEP; ++c) areg[c] = ldA(c);
#pragma unroll
  for (int c = 0; c < NCH; ++c) {
    f16x8 a = areg[c % DEP];
#pragma unroll
    for (int t = 0; t < TPW; ++t) {
      f16x8 b = *(const f16x8*)(bufp + (size_t)(c*TPW + t)*512 + lane*8);
      acc[t] = __builtin_amdgcn_mfma_f32_16x16x32_f16(a, b, acc[t], 0, 0, 0);
    }
    if (c + DEP < NCH) areg[c % DEP] = ldA(c + DEP);
  }

  if (HASE) {   // E-correction (K=8 embedding part)
#pragma unroll
    for (int t = 0; t < TPW; ++t) {
      const int colL = ct0 + t*16 + (lane & 15);
      float w[8];
#pragma unroll
      for (int j = 0; j < 8; ++j) w[j] = WeP[j*ldwe + colL];
#pragma unroll
      for (int m = 0; m < 4; ++m) {
        const int rr = rows0 + wr*16 + ((lane >> 4) << 2) + m;
        float s = 0.f;
#pragma unroll
        for (int j = 0; j < 8; ++j) s = __builtin_fmaf(ex[rr*8 + j], w[j], s);
        acc[t][m] += s;
      }
    }
  }
  fe(wr, lane, acc);
}

// ---------------- epilogues ----------------
template<int TPW>
struct GateEpiM {
  const float* cin; u16* ho; float* co; u16* coh; const float* bias_pk;
  int rows0; int ct0;
  __device__ void operator()(int wr, int lane, f32x4 (&acc)[TPW]) const {
    const int rbase = rows0 + wr*16 + ((lane >> 4) << 2);
#pragma unroll
    for (int gi = 0; gi < TPW/4; ++gi) {
      const int cb = ct0 + gi*64;
      const int h = (((cb & 1023) >> 6) << 4) + (lane & 15);
      float b[4];
#pragma unroll
      for (int t = 0; t < 4; ++t) b[t] = bias_pk[cb + t*16 + (lane & 15)];
#pragma unroll
      for (int m = 0; m < 4; ++m) {
        const size_t ix = (size_t)(rbase + m)*H_ + h;
        float gI = sig_(acc[gi*4+0][m] + b[0]);
        float gF = sig_(acc[gi*4+1][m] + b[1]);
        float gG = tanh_(acc[gi*4+2][m] + b[2]);
        float gO = sig_(acc[gi*4+3][m] + b[3]);
        float cn = gF*cin[ix] + gI*gG;
        ho[ix] = f2h(gO*tanh_(cn));
        co[ix] = cn;
        coh[ix] = f2h(cn);
      }
    }
  }
};

struct MlpEpiH {
  u16* dst; const float* b1; int rows0; int ct0;
  __device__ void operator()(int wr, int lane, f32x4 (&acc)[2]) const {
    const int rbase = rows0 + wr*16 + ((lane >> 4) << 2);
#pragma unroll
    for (int t = 0; t < 2; ++t) {
      const int c = ct0 + t*16 + (lane & 15);
      const float bb = b1[c];
#pragma unroll
      for (int m = 0; m < 4; ++m)
        dst[(size_t)(rbase + m)*512 + c] = f2h(fmaxf(acc[t][m] + bb, 0.f));
    }
  }
};

// ---- fused p-MLP2 + head + softmax + mix (fp16 M/WB/h, fp32 c) ----
__device__ __forceinline__ void stage_F2(
    int rowbase,
    const u16* M, const u16* WBpk, const float* b2,
    const float* W3, const float* b3,
    const u16* lh, const float* lc,
    const u16* ghp, const float* gcp,
    u16* ghc, float* gcc)
{
  const int w = threadIdx.x >> 6, lane = threadIdx.x & 63;
  const int r0 = rowbase + w*2;
  const u16* a0 = M + (size_t)r0*512;
  const u16* a1 = a0 + 512;
  float m0[4] = {0.f,0.f,0.f,0.f}, m1[4] = {0.f,0.f,0.f,0.f};
  for (int k0 = 0; k0 < 512; k0 += 4) {
    f16x4 x0 = *(const f16x4*)&a0[k0];
    f16x4 x1 = *(const f16x4*)&a1[k0];
#pragma unroll
    for (int j = 0; j < 4; ++j) {
      f16x4 wv = *(const f16x4*)&WBpk[(size_t)(k0+j)*256 + lane*4];
      float w0 = (float)wv[0], w1 = (float)wv[1], w2 = (float)wv[2], w3v = (float)wv[3];
      float xv0 = (float)x0[j], xv1 = (float)x1[j];
      m0[0] = __builtin_fmaf(xv0, w0, m0[0]);
      m0[1] = __builtin_fmaf(xv0, w1, m0[1]);
      m0[2] = __builtin_fmaf(xv0, w2, m0[2]);
      m0[3] = __builtin_fmaf(xv0, w3v, m0[3]);
      m1[0] = __builtin_fmaf(xv1, w0, m1[0]);
      m1[1] = __builtin_fmaf(xv1, w1, m1[1]);
      m1[2] = __builtin_fmaf(xv1, w2, m1[2]);
      m1[3] = __builtin_fmaf(xv1, w3v, m1[3]);
    }
  }
  float4 b = *(const float4*)&b2[lane*4];
  float bb2[4] = {b.x,b.y,b.z,b.w};
#pragma unroll
  for (int j = 0; j < 4; ++j) {
    m0[j] = fmaxf(m0[j]+bb2[j], 0.f);
    m1[j] = fmaxf(m1[j]+bb2[j], 0.f);
  }
  float4 w30 = *(const float4*)&W3[lane*4];
  float4 w31 = *(const float4*)&W3[256 + lane*4];
  float w0v[4] = {w30.x,w30.y,w30.z,w30.w};
  float w1v[4] = {w31.x,w31.y,w31.z,w31.w};
  float d00=0.f, d01=0.f, d10=0.f, d11=0.f;
#pragma unroll
  for (int j = 0; j < 4; ++j) {
    d00 = __builtin_fmaf(m0[j], w0v[j], d00);
    d01 = __builtin_fmaf(m0[j], w1v[j], d01);
    d10 = __builtin_fmaf(m1[j], w0v[j], d10);
    d11 = __builtin_fmaf(m1[j], w1v[j], d11);
  }
#pragma unroll
  for (int off = 32; off; off >>= 1) {
    d00 += __shfl_xor(d00, off, 64); d01 += __shfl_xor(d01, off, 64);
    d10 += __shfl_xor(d10, off, 64); d11 += __shfl_xor(d11, off, 64);
  }
  d00 += b3[0]; d01 += b3[1]; d10 += b3[0]; d11 += b3[1];
  float mxa = fmaxf(d00, d01), mxb = fmaxf(d10, d11);
  float e00 = __expf(d00-mxa), e01 = __expf(d01-mxa);
  float e10 = __expf(d10-mxb), e11 = __expf(d11-mxb);
  float ia = 1.f/(e00+e01), ib = 1.f/(e10+e11);
  float p0a = e00*ia, p1a = e01*ia;
  float p0b = e10*ib, p1b = e11*ib;
#pragma unroll
  for (int rr = 0; rr < 2; ++rr) {
    const float p0 = rr ? p0b : p0a, p1 = rr ? p1b : p1a;
    const size_t ix = (size_t)(r0+rr)*H_ + lane*4;
    f16x4 lv = *(const f16x4*)&lh[ix];
    f16x4 gv = *(const f16x4*)&ghp[ix];
    f16x4 oh;
#pragma unroll
    for (int j = 0; j < 4; ++j)
      oh[j] = (_Float16)(p0*(float)lv[j] + p1*(float)gv[j]);
    *(f16x4*)&ghc[ix] = oh;
    float4 lcv = *(const float4*)&lc[ix];
    float4 gcv = *(const float4*)&gcp[ix];
    float4 oc;
    oc.x = p0*lcv.x + p1*gcv.x; oc.y = p0*lcv.y + p1*gcv.y;
    oc.z = p0*lcv.z + p1*gcv.z; oc.w = p0*lcv.w + p1*gcv.w;
    *(float4*)&gcc[ix] = oc;
  }
}

// -------- output projection -> staging buffer [r][t&15][90] --------
__device__ __forceinline__ void stage_OUTS(
    const u16* gh2c, const float* WOUT, const float* BOUT,
    float* ostg, int rbase, int tt)
{
  const int w = threadIdx.x >> 6, lane = threadIdx.x & 63;
  const bool two = lane < (V_ - 64);
#pragma unroll
  for (int rr = 0; rr < 2; ++rr) {
    const int r = rbase + w*2 + rr;
    const u16* arow = gh2c + (size_t)r * H_;
    float acc0 = 0.f, acc1 = 0.f;
    for (int k0 = 0; k0 < 256; k0 += 8) {
      f16x8 a8 = *(const f16x8*)&arow[k0];
#pragma unroll
      for (int j = 0; j < 8; ++j) {
        const float av = (float)a8[j];
        const float* wr_ = &WOUT[(size_t)(k0+j)*96];
        acc0 = __builtin_fmaf(av, wr_[lane], acc0);
        if (two) acc1 = __builtin_fmaf(av, wr_[64+lane], acc1);
      }
    }
    float* dst = &ostg[((size_t)r*16 + (tt & 15))*90];
    dst[lane] = acc0 + BOUT[lane];
    if (two) dst[64+lane] = acc1 + BOUT[64+lane];
  }
}

// -------- flush 16 t-columns: full-line 64B writes to out --------
__device__ __forceinline__ void flush_out(
    const float* ostg, float* out, int rbase, int tb0)
{
  for (int i = threadIdx.x; i < 16*90; i += NTHR) {
    const int rr = i / 90, v = i - rr*90;
    const int r = rbase + rr;
    const float* src = &ostg[((size_t)r*16)*90 + v];
    float tmp[16];
#pragma unroll
    for (int tb = 0; tb < 16; ++tb) tmp[tb] = src[tb*90];
    float* dst = &out[((size_t)r*V_ + v)*T_ + tb0];
#pragma unroll
    for (int q = 0; q < 4; ++q)
      ((float4*)dst)[q] = make_float4(tmp[q*4], tmp[q*4+1], tmp[q*4+2], tmp[q*4+3]);
  }
}

// ---------------- setup (weight layouts identical to R12/R14) ----------------
__global__ void k_setup(InP in, float* __restrict__ ws)
{
  const size_t nthr = (size_t)gridDim.x * blockDim.x;
  const size_t t0 = (size_t)blockIdx.x * blockDim.x + threadIdx.x;

  for (size_t i = t0; i < OFF_M1H; i += nthr) ws[i] = 0.f;  // all states zero
  for (size_t i = t0; i < 8192; i += nthr) ((unsigned*)(ws + OFF_BAR))[i] = 0u;

  for (size_t i = t0; i < (size_t)B_*8; i += nthr) {
    int r = (int)(i >> 3), j = (int)(i & 7);
    ws[OFF_EX + i] = in.emb[(size_t)in.seq[(size_t)r*T_]*8 + j];
  }

  {
    u16* dst = (u16*)(ws + OFF_WG1PK);
    for (size_t i = t0; i < (size_t)16*8*8*512; i += nthr) {
      int e = (int)(i & 7), lane = (int)((i >> 3) & 63);
      int tile = (int)((i >> 9) & 7), ck = (int)((i >> 12) & 7), blk = (int)(i >> 15);
      int col = blk*128 + tile*16 + (lane & 15);
      int k = ck*32 + ((lane >> 4) << 3) + e;
      int cell = col >> 10, q = col & 1023;
      int h = ((q >> 6) << 4) + (q & 15), g = (q >> 4) & 3, R = g*256 + h;
      dst[i] = f2h((cell ? in.l1_Whh : in.g1_Whh)[(size_t)R*256 + k]);
    }
  }
  for (size_t i = t0; i < (size_t)8*2048; i += nthr) {
    int j = (int)(i >> 11), p = (int)(i & 2047);
    int cell = p >> 10, q = p & 1023;
    int h = ((q >> 6) << 4) + (q & 15), g = (q >> 4) & 3, R = g*256 + h;
    ws[OFF_WE1 + (size_t)j*2048 + p] = (cell ? in.l1_Wih : in.g1_Wih)[(size_t)R*8 + j];
  }
  for (size_t i = t0; i < 2048; i += nthr) {
    int p = (int)i, cell = p >> 10, q = p & 1023;
    int h = ((q >> 6) << 4) + (q & 15), g = (q >> 4) & 3, R = g*256 + h;
    ws[OFF_BG1 + i] = cell ? (in.l1_bih[R] + in.l1_bhh[R]) : (in.g1_bih[R] + in.g1_bhh[R]);
  }

  for (int which = 0; which < 2; ++which) {
    u16* dst = (u16*)(ws + (which ? OFF_WG2PK : OFF_WL2PK));
    const float* Wih = which ? in.g2_Wih : in.l2_Wih;
    const float* Whh = which ? in.g2_Whh : in.l2_Whh;
    for (size_t i = t0; i < (size_t)16*16*4*512; i += nthr) {
      int e = (int)(i & 7), lane = (int)((i >> 3) & 63);
      int tile = (int)((i >> 9) & 3), ck = (int)((i >> 11) & 15), blk = (int)(i >> 15);
      int col = blk*64 + tile*16 + (lane & 15);
      int k = ck*32 + ((lane >> 4) << 3) + e;
      int h = ((col >> 6) << 4) + (col & 15), g = (col >> 4) & 3, R = g*256 + h;
      float w = (k < 256) ? Wih[(size_t)R*256 + k] : Whh[(size_t)R*256 + (k-256)];
      dst[i] = f2h(w);
    }
  }
  for (size_t i = t0; i < 2*1024; i += nthr) {
    int which = (int)(i >> 10), p = (int)(i & 1023);
    int h = ((p >> 6) << 4) + (p & 15), g = (p >> 4) & 3, R = g*256 + h;
    float v = which ? (in.g2_bih[R] + in.g2_bhh[R]) : (in.l2_bih[R] + in.l2_bhh[R]);
    ws[(which ? OFF_BG2 : OFF_BL2) + p] = v;
  }

  for (int which = 0; which < 2; ++which) {
    u16* dst = (u16*)(ws + (which ? OFF_WP2PK : OFF_WP1PK));
    const float* W = which ? in.p2_W1 : in.p1_W1;
    for (size_t i = t0; i < (size_t)16*32*2*512; i += nthr) {
      int e = (int)(i & 7), lane = (int)((i >> 3) & 63);
      int tile = (int)((i >> 9) & 1), ck = (int)((i >> 10) & 31), blk = (int)(i >> 15);
      int col = blk*32 + tile*16 + (lane & 15);
      int k = ck*32 + ((lane >> 4) << 3) + e;
      dst[i] = f2h(W[(size_t)col*1032 + 8 + k]);
    }
  }
  for (size_t i = t0; i < (size_t)2*8*512; i += nthr) {
    int which = (int)(i / (8*512));
    int idx = (int)(i - (size_t)which*8*512);
    int j = idx >> 9, p = idx & 511;
    const float* W = which ? in.p2_W1 : in.p1_W1;
    ws[(which ? OFF_WEP2 : OFF_WEP1) + (size_t)j*512 + p] = W[(size_t)p*1032 + j];
  }

  for (size_t i = t0; i < (size_t)2*512*256; i += nthr) {
    int which = (int)(i / (512*256));
    int idx = (int)(i - (size_t)which*512*256);
    int k = idx >> 8, n = idx & 255;
    const float* W = which ? in.p2_W2 : in.p1_W2;
    ((u16*)(ws + (which ? OFF_WB2 : OFF_WB1)))[idx] = f2h(W[(size_t)n*512 + k]);
  }
  for (size_t i = t0; i < (size_t)256*96; i += nthr) {
    int k = (int)(i / 96), c = (int)(i - (size_t)k*96);
    float v = 0.f;
    if (c < V_) v = 0.5f*(in.gfc_W[(size_t)c*256 + k] + in.lfc_W[(size_t)c*256 + k]);
    ws[OFF_WOUT + i] = v;
  }
  for (size_t i = t0; i < 96; i += nthr)
    ws[OFF_BOUT + i] = (i < V_) ? 0.5f*(in.gfc_b[i] + in.lfc_b[i]) : 0.f;
}

// -------- replicate packed weights into 8 per-XCD copies (separate launch) ----
__global__ void k_rep(float* __restrict__ ws)
{
  const size_t nthr = (size_t)gridDim.x * blockDim.x;
  const size_t t0 = (size_t)blockIdx.x * blockDim.x + threadIdx.x;
  unsigned* dst0 = (unsigned*)(ws + OFF_WREP);
  for (size_t i = t0; i < (size_t)8*REP_U32; i += nthr) {
    const size_t rep = i / REP_U32, q = i - rep*REP_U32;
    const size_t blob = q / 262144, w = q - blob*262144;
    const size_t src_off = (blob == 0) ? OFF_WG1PK : (blob == 1) ? OFF_WL2PK :
                           (blob == 2) ? OFF_WG2PK : (blob == 3) ? OFF_WP1PK : OFF_WP2PK;
    dst0[i] = ((const unsigned*)(ws + src_off))[w];
  }
}

// ------- main: 3-phase pipeline, dbuf DMA-at-phase-start, per-XCD weights -------
__global__ __launch_bounds__(NTHR) void k_main(InP in, float* ws, float* __restrict__ out,
                                               int use_rep)
{
  __shared__ __attribute__((aligned(16))) u16 sB0[32768];   // 64KB buffer 0
  extern __shared__ u16 dynB[];                             // 64KB buffer 1
  __shared__ unsigned s_slot;

  u16*  GH1C = (u16*)(ws + OFF_GH1C);
  u16*  GH1P = (u16*)(ws + OFF_GH1P);
  u16*  LH1  = (u16*)(ws + OFF_LH1);
  u16*  GH2C = (u16*)(ws + OFF_GH2C);
  u16*  GH2P = (u16*)(ws + OFF_GH2P);
  u16*  LH2  = (u16*)(ws + OFF_LH2);
  u16*  GC1PH= (u16*)(ws + OFF_GC1PH);
  u16*  LC1H = (u16*)(ws + OFF_LC1H);
  u16*  GC2PH= (u16*)(ws + OFF_GC2PH);
  u16*  LC2H = (u16*)(ws + OFF_LC2H);
  float* GC1C = ws + OFF_GC1C;  float* GC1P = ws + OFF_GC1P;
  float* LC1  = ws + OFF_LC1;
  float* GC2C = ws + OFF_GC2C;  float* GC2P = ws + OFF_GC2P;
  float* LC2  = ws + OFF_LC2;
  u16*   M1H  = (u16*)(ws + OFF_M1H);
  u16*   M2H  = (u16*)(ws + OFF_M2H);
  float* OSTG = ws + OFF_OSTG;
  float* EXB  = ws + OFF_EX;
  const u16* WB1PK = (const u16*)(ws + OFF_WB1);
  const u16* WB2PK = (const u16*)(ws + OFF_WB2);
  const float* WE1  = ws + OFF_WE1;  const float* BG1P = ws + OFF_BG1;
  const float* BL2P = ws + OFF_BL2;  const float* BG2P = ws + OFF_BG2;
  const float* WEP1 = ws + OFF_WEP1; const float* WEP2 = ws + OFF_WEP2;
  const float* WOUT = ws + OFF_WOUT; const float* BOUT = ws + OFF_BOUT;

  unsigned xcc;
  asm volatile("s_getreg_b32 %0, hwreg(HW_REG_XCC_ID)" : "=s"(xcc));
  xcc &= 7u;

  // per-XCD weight replica bases (fall back to canonical copy if no room)
  const u16* WR = (const u16*)(ws + OFF_WREP) + (size_t)xcc * (5u*524288u);
  const u16* WG1X = use_rep ? WR             : (const u16*)(ws + OFF_WG1PK);
  const u16* WL2X = use_rep ? WR + 524288u   : (const u16*)(ws + OFF_WL2PK);
  const u16* WG2X = use_rep ? WR + 1048576u  : (const u16*)(ws + OFF_WG2PK);
  const u16* WP1X = use_rep ? WR + 1572864u  : (const u16*)(ws + OFF_WP1PK);
  const u16* WP2X = use_rep ? WR + 2097152u  : (const u16*)(ws + OFF_WP2PK);

  unsigned* barx = ((unsigned*)(ws + OFF_BAR)) + xcc*1024;
  unsigned* arr  = barx;
  unsigned* reg  = barx + 544;
  if (threadIdx.x == 0)
    s_slot = __hip_atomic_fetch_add(reg, 1u, __ATOMIC_RELAXED, __HIP_MEMORY_SCOPE_AGENT);
  __syncthreads();
  const int slot  = (int)(s_slot & 31u);
  const int rows0 = (int)xcc * 128;
  const int s2 = slot & 15;
  unsigned ep = 0;
  int wb = 0;   // parity: 0 -> compute from sB0, fetch into dynB

  // prologue: fetch first P_A weights into sB0, drain
  if (slot < 16) dma64(WG1X + (size_t)slot*32768, sB0);
  else           dma64(WG2X + (size_t)s2*32768, sB0);
  asm volatile("s_waitcnt vmcnt(0)" ::: "memory");
  __syncthreads();

  for (int n = 0; n <= T_; ++n) {
    const int sel = n & 1;
    const float* ex  = EXB + sel*(B_*8);
    const float* exm = EXB + (sel^1)*(B_*8);
    u16* lh1o = LH1 + sel*(B_*H_);   u16* lh1n = LH1 + (sel^1)*(B_*H_);
    float* lc1o = LC1 + sel*S_;      float* lc1n = LC1 + (sel^1)*S_;
    u16* lc1nh = LC1H + (sel^1)*(B_*H_);
    u16* lh2o = LH2 + sel*(B_*H_);   u16* lh2n = LH2 + (sel^1)*(B_*H_);
    float* lc2o = LC2 + sel*S_;      float* lc2n = LC2 + (sel^1)*S_;
    u16* lc2oh = LC2H + sel*(B_*H_); u16* lc2nh = LC2H + (sel^1)*(B_*H_);

    u16* bC; u16* bF;

    // ===== P_A: issue P_B weights, compute gates1 || g2(n-1) =====
    bC = wb ? dynB : sB0; bF = wb ? sB0 : dynB;
    if (slot < 16) dma64(WP1X + (size_t)s2*32768, bF);
    else           dma64(WP2X + (size_t)s2*32768, bF);
    if (slot < 16) {
      if (n < T_) {
        const int ct0 = slot*128;
        const int cell = slot >> 3;
        GateEpiM<8> epi{ cell ? lc1o : GC1C,
                         cell ? lh1n : GH1P,
                         cell ? lc1n : GC1P,
                         cell ? lc1nh : GC1PH,
                         BG1P, rows0, ct0 };
        mm_lds<8,1,true,8>(bC, cell ? lh1o : GH1C, nullptr, nullptr, nullptr,
                           WE1, 2048, ex, rows0, ct0, epi);
      }
    } else if (n >= 1) {
      const int ct0 = s2*64;
      GateEpiM<4> epi{ GC2C, GH2P, GC2P, GC2PH, BG2P, rows0, ct0 };
      mm_lds<16,2,false,4>(bC, GH1C, GH2C, nullptr, nullptr,
                           nullptr, 0, nullptr, rows0, ct0, epi);
    }
    gbar_x(arr, slot, ++ep);
    wb ^= 1;

    // ===== P_B: issue P_C / next P_A weights, compute MLP1 || MLP2(n-1) =====
    bC = wb ? dynB : sB0; bF = wb ? sB0 : dynB;
    if (slot < 16) dma64(WL2X + (size_t)slot*32768, bF);
    else           dma64(WG2X + (size_t)s2*32768, bF);
    if (slot < 16) {
      if (n < T_) {
        const int ct0 = s2*32;
        MlpEpiH epi{ M1H, in.p1_b1, rows0, ct0 };
        mm_lds<32,4,true,2>(bC, GH1P, GC1PH, lh1n, lc1nh,
                            WEP1, 512, ex, rows0, ct0, epi);
      }
    } else if (n >= 1) {
      const int ct0 = s2*32;
      MlpEpiH epi{ M2H, in.p2_b1, rows0, ct0 };
      mm_lds<32,4,true,2>(bC, GH2P, GC2PH, lh2o, lc2oh,
                          WEP2, 512, exm, rows0, ct0, epi);
    }
    gbar_x(arr, slot, ++ep);
    wb ^= 1;

    // ===== P_C: slots<16 issue next P_A weights + compute l2; others F2 =====
    bC = wb ? dynB : sB0; bF = wb ? sB0 : dynB;
    if (slot < 16) {
      dma64(WG1X + (size_t)slot*32768, bF);
      if (n < T_) {
        const int ct0 = slot*64;
        GateEpiM<4> epi{ lc2o, lh2n, lc2n, lc2nh, BL2P, rows0, ct0 };
        mm_lds<16,2,false,4>(bC, lh1n, lh2o, nullptr, nullptr,
                             nullptr, 0, nullptr, rows0, ct0, epi);
      }
    } else if (slot < 24) {
      if (n < T_) {
        const int rb = rows0 + (slot-16)*16;
        stage_F2(rb, M1H, WB1PK, in.p1_b2, in.p1_W3, in.p1_b3,
                 lh1n, lc1n, GH1P, GC1P, GH1C, GC1C);
        if (n + 1 < T_ && threadIdx.x < 128) {
          const int r = rb + (threadIdx.x >> 3), j = threadIdx.x & 7;
          EXB[(sel^1)*(B_*8) + r*8 + j] =
              in.emb[(size_t)in.seq[(size_t)r*T_ + n + 1]*8 + j];
        }
      }
    } else {
      if (n >= 1) {
        const int rb = rows0 + (slot-24)*16;
        stage_F2(rb, M2H, WB2PK, in.p2_b2, in.p2_W3, in.p2_b3,
                 lh2o, lc2o, GH2P, GC2P, GH2C, GC2C);
        __syncthreads();
        stage_OUTS(GH2C, WOUT, BOUT, OSTG, rb, n-1);
        if (((n-1) & 15) == 15) {
          __syncthreads();
          flush_out(OSTG, out, rb, n-16);
        }
      }
    }
    gbar_x(arr, slot, ++ep);
    if (slot < 16) wb ^= 1;      // slots>=16: no P_C fetch -> keep parity
  }
}

// ---------------- host ----------------
extern "C" void kernel_launch(void* const* d_in, const int* in_sizes, int n_in,
                              void* d_out, int out_size, void* d_ws, size_t ws_size,
                              hipStream_t stream)
{
  if (ws_size < WS_FLOATS * sizeof(float)) return;
  const int use_rep = (ws_size >= WS_FULL * sizeof(float)) ? 1 : 0;

  InP in;
  in.seq    = (const int*)  d_in[0];
  in.emb    = (const float*)d_in[1];
  in.g1_Wih = (const float*)d_in[2];  in.g1_Whh = (const float*)d_in[3];
  in.g1_bih = (const float*)d_in[4];  in.g1_bhh = (const float*)d_in[5];
  in.g2_Wih = (const float*)d_in[6];  in.g2_Whh = (const float*)d_in[7];
  in.g2_bih = (const float*)d_in[8];  in.g2_bhh = (const float*)d_in[9];
  in.l1_Wih = (const float*)d_in[10]; in.l1_Whh = (const float*)d_in[11];
  in.l1_bih = (const float*)d_in[12]; in.l1_bhh = (const float*)d_in[13];
  in.l2_Wih = (const float*)d_in[14]; in.l2_Whh = (const float*)d_in[15];
  in.l2_bih = (const float*)d_in[16]; in.l2_bhh = (const float*)d_in[17];
  in.p1_W1  = (const float*)d_in[18]; in.p1_b1  = (const float*)d_in[19];
  in.p1_W2  = (const float*)d_in[20]; in.p1_b2  = (const float*)d_in[21];
  in.p1_W3  = (const float*)d_in[22]; in.p1_b3  = (const float*)d_in[23];
  in.p2_W1  = (const float*)d_in[24]; in.p2_b1  = (const float*)d_in[25];
  in.p2_W2  = (const float*)d_in[26]; in.p2_b2  = (const float*)d_in[27];
  in.p2_W3  = (const float*)d_in[28]; in.p2_b3  = (const float*)d_in[29];
  in.gfc_W  = (const float*)d_in[30]; in.gfc_b  = (const float*)d_in[31];
  in.lfc_W  = (const float*)d_in[32]; in.lfc_b  = (const float*)d_in[33];

  float* ws  = (float*)d_ws;
  float* out = (float*)d_out;

  k_setup<<<512, 256, 0, stream>>>(in, ws);
  if (use_rep) k_rep<<<512, 256, 0, stream>>>(ws);
  k_main <<<NBLK, NTHR, 65536, stream>>>(in, ws, out, use_rep);
}